// Round 2
// baseline (1477.690 us; speedup 1.0000x reference)
//
#include <hip/hip_runtime.h>
#include <cmath>

// ---- problem constants ----
#define NBS 8
#define NC 20
#define NFH 480
#define NFW 640
#define NHS 240
#define NWS 320
#define NM 480
#define NPIX (NM * NM)   // 230400
#define NVR 100
#define NPIXELS (NBS * NHS * NWS)  // 614400
#define PPB (NHS * NWS)            // 76800 pixels per batch
#define ESTRIDE 20                 // entry record: x,y,z,flag + 16 sem
#define TILE 6
#define NTILE 17                   // ceil(100/6)
#define CSTR 401                   // LDS column stride (odd -> banks spread)

// ---- d_out layout (float element offsets) ----
// out = [translated (8,20,480,480) | map_pred | map_pred_stair | poses (8,3)]
constexpr long long T_OFF    = 0LL;
constexpr long long P_OFF    = 36864000LL;   // 8*20*230400
constexpr long long S_OFF    = 73728000LL;
constexpr long long POSE_OFF = 110592000LL;

// scratch lives in the P region (dead until k_pred, which runs last)
constexpr long long SMAP_OFF = P_OFF;                     // 8*19*10000
constexpr long long PAR_OFF  = SMAP_OFF + 1520000LL;      // 64 floats
constexpr long long TS_OFF   = PAR_OFF + 64LL;            // 8*230400 tstair ch0
constexpr long long REC_OFF  = TS_OFF + 1843200LL;        // 614400 float4 records
constexpr long long ENT_OFF  = REC_OFF + 2457600LL;       // 614400*20 entries
constexpr long long CNT_OFF  = ENT_OFF + 12288000LL;      // 80000 u32 counts
constexpr long long OFF2_OFF = CNT_OFF + 80000LL;         // 80000 u32 offsets
constexpr long long CUR_OFF  = OFF2_OFF + 80000LL;        // 80000 u32 cursors
// end = P_OFF + 18,348,864 < P_OFF + 36,864,000  OK

__device__ __forceinline__ float clamp01(float x) {
    return fminf(fmaxf(x, 0.0f), 1.0f);
}

// shared projection math: MUST be the single source of truth for pos/alive
__device__ __forceinline__ void project_px(const float* __restrict__ ob, float ev,
                                           float camf, int iy, int ix,
                                           float& posx, float& posy, float& posz,
                                           bool& alive, bool& semz) {
    float depth = ob[(3LL * NFH + 2 * iy) * NFW + 2 * ix];
    float th = ev * 0.017453292519943295f;
    float ct = cosf(th), st = sinf(th);
    float X = ((float)(2 * ix) - 319.5f) * depth / camf;
    float Z = ((float)(479 - 2 * iy) - 239.5f) * depth / camf;
    float Yr = ct * depth - st * Z;
    float Zr = st * depth + ct * Z + 88.0f;
    float Xs = X + 250.0f;
    float cx = ((Xs / 5.0f) - 50.0f) / 100.0f * 2.0f;
    float cy = ((Yr / 5.0f) - 50.0f) / 100.0f * 2.0f;
    float cz = ((Zr / 5.0f) - 16.0f) / 48.0f * 2.0f;
    posx = (cx * 100.0f) / 2.0f + 50.0f;
    posy = (cy * 100.0f) / 2.0f + 50.0f;
    posz = (cz * 48.0f) / 2.0f + 24.0f;
    alive = (posx > 0.0f) && (posx < 100.0f) &&
            (posy > 0.0f) && (posy < 100.0f) &&
            (posz > 0.0f) && (posz < 48.0f);
    semz = (posz > 12.0f) && (posz < 35.0f);
}

// ---------------- K1: poses + affine params ----------------
__global__ void k_pose(const float* __restrict__ pose_obs,
                       const float* __restrict__ poses_last,
                       float* __restrict__ outp) {
    int b = threadIdx.x;
    if (b >= NBS) return;
    float* pose_out = outp + POSE_OFF;
    float* par = outp + PAR_OFF;
    const float DEGf = 57.29577951308232f;
    float tr = poses_last[b * 3 + 2] / DEGf;
    float s_tr = sinf(tr), c_tr = cosf(tr);
    float ny = poses_last[b * 3 + 1] + pose_obs[b * 3 + 0] * s_tr + pose_obs[b * 3 + 1] * c_tr;
    float nx = poses_last[b * 3 + 0] + pose_obs[b * 3 + 0] * c_tr - pose_obs[b * 3 + 1] * s_tr;
    float no = poses_last[b * 3 + 2] + pose_obs[b * 3 + 2] * DEGf;
    no = fmodf(no - 180.0f, 360.0f) + 180.0f;
    no = fmodf(no + 180.0f, 360.0f) - 180.0f;
    pose_out[b * 3 + 0] = nx;
    pose_out[b * 3 + 1] = ny;
    pose_out[b * 3 + 2] = no;
    float stx = -((nx * 100.0f) / 5.0f - 240.0f) / 240.0f;
    float sty = -((ny * 100.0f) / 5.0f - 240.0f) / 240.0f;
    float stt = ((90.0f - no) * 3.14159265358979323846f) / 180.0f;
    par[b * 4 + 0] = cosf(stt);
    par[b * 4 + 1] = sinf(stt);
    par[b * 4 + 2] = stx;
    par[b * 4 + 3] = sty;
    if (b == 0) {
        int sy = (int)((ny * 100.0f) / 5.0f);   // truncation matches astype(int32)
        int sx = (int)((nx * 100.0f) / 5.0f);
        sy = min(max(sy, 30), NM - 31);
        sx = min(max(sx, 30), NM - 31);
        par[32] = (float)sy;
        par[33] = (float)sx;
    }
}

// ---------------- K2a: project pixels, write rec, count per bucket ----------------
__global__ void k_count(const float* __restrict__ obs,
                        const float* __restrict__ eve, float camf,
                        unsigned int* __restrict__ counts,
                        float4* __restrict__ rec) {
    int tid = blockIdx.x * blockDim.x + threadIdx.x;
    if (tid >= NPIXELS) return;
    int b = tid / PPB;
    int p = tid % PPB;
    int iy = p / NWS, ix = p % NWS;
    const float* ob = obs + (long long)b * NC * NFH * NFW;
    float posx, posy, posz;
    bool alive, semz;
    project_px(ob, eve[b], camf, iy, ix, posx, posy, posz, alive, semz);
    float flag = alive ? (semz ? 2.0f : 1.0f) : 0.0f;
    rec[tid] = make_float4(posx, posy, posz, flag);
    if (!alive) return;
    int fx = (int)floorf(posx);   // in [0,99]
    int fy = (int)floorf(posy);
    atomicAdd(&counts[b * 10000 + fx * 100 + fy], 1u);
}

// ---------------- K2b: per-batch exclusive prefix sum (single-pass block scan) ----------------
__global__ void __launch_bounds__(1024) k_scan(const unsigned int* __restrict__ counts,
                                               unsigned int* __restrict__ offs,
                                               unsigned int* __restrict__ curs) {
    int b = blockIdx.x;          // 8 blocks
    int t = threadIdx.x;         // 1024
    int lane = t & 63, wid = t >> 6;
    const unsigned int* cb = counts + b * 10000;
    unsigned int base_i = (unsigned int)t * 10u;
    unsigned int v[10];
    unsigned int s = 0;
#pragma unroll
    for (int k = 0; k < 10; ++k) {
        unsigned int i = base_i + (unsigned int)k;
        unsigned int x = (i < 10000u) ? cb[i] : 0u;
        v[k] = s;                // exclusive within thread
        s += x;
    }
    unsigned int incl = s;
#pragma unroll
    for (int d = 1; d < 64; d <<= 1) {
        unsigned int u = __shfl_up(incl, d);
        if (lane >= d) incl += u;
    }
    __shared__ unsigned int wtot[16];
    __shared__ unsigned int wexc[16];
    if (lane == 63) wtot[wid] = incl;
    __syncthreads();
    if (t == 0) {
        unsigned int a = 0;
        for (int i = 0; i < 16; ++i) { wexc[i] = a; a += wtot[i]; }
    }
    __syncthreads();
    unsigned int tbase = wexc[wid] + (incl - s);
#pragma unroll
    for (int k = 0; k < 10; ++k) {
        unsigned int i = base_i + (unsigned int)k;
        if (i < 10000u) {
            unsigned int e = tbase + v[k];
            offs[b * 10000 + i] = e;
            curs[b * 10000 + i] = e;
        }
    }
}

// ---------------- K2c: fill 80B bucket entries (pos + inlined pooled sem) ----------------
__global__ void k_fill(const float* __restrict__ obs,
                       const float4* __restrict__ rec,
                       unsigned int* __restrict__ curs,
                       float* __restrict__ entries) {
    int tid = blockIdx.x * blockDim.x + threadIdx.x;
    if (tid >= NPIXELS) return;
    float4 r = rec[tid];
    if (r.w == 0.0f) return;
    int b = tid / PPB;
    int p = tid % PPB;
    int iy = p / NWS, ix = p % NWS;
    int fx = (int)floorf(r.x);
    int fy = (int)floorf(r.y);
    unsigned int slot = atomicAdd(&curs[b * 10000 + fx * 100 + fy], 1u);
    float4 sem4[4];
#pragma unroll
    for (int g = 0; g < 4; ++g) sem4[g] = make_float4(0.f, 0.f, 0.f, 0.f);
    if (r.w == 2.0f) {  // sem needed: 2x2 mean pool of channels 4..19
        const float* ob = obs + (long long)b * NC * NFH * NFW;
        float sem[16];
#pragma unroll
        for (int k = 0; k < 16; ++k) {
            const float* q = ob + ((long long)(4 + k) * NFH + 2 * iy) * NFW + 2 * ix;
            sem[k] = (q[0] + q[1] + q[NFW] + q[NFW + 1]) * 0.25f;
        }
#pragma unroll
        for (int g = 0; g < 4; ++g)
            sem4[g] = make_float4(sem[4 * g], sem[4 * g + 1], sem[4 * g + 2], sem[4 * g + 3]);
    }
    float4* ep = (float4*)(entries + ((long long)b * PPB + slot) * ESTRIDE);
    ep[0] = make_float4(r.x, r.y, r.z, 0.f);
#pragma unroll
    for (int g = 0; g < 4; ++g) ep[1 + g] = sem4[g];
}

// ---------------- K2d: tiled gather-accumulate + fused z-projection ----------------
// One 256-thread block per 6x6 column tile. Entries of the (TILE+1)^2 halo buckets
// are flattened into <=7 contiguous ranges (one per bx) for dense lane utilization.
// Each entry visited once; scatters to all its in-tile corners via LDS atomics.
__global__ void __launch_bounds__(256) k_accum(const float* __restrict__ entries,
                                               const unsigned int* __restrict__ counts,
                                               const unsigned int* __restrict__ offs,
                                               float* __restrict__ smap) {
    int tileId = blockIdx.x;           // 8 * 17 * 17
    int b = tileId / (NTILE * NTILE);
    int txy = tileId % (NTILE * NTILE);
    int tx = txy / NTILE, ty = txy % NTILE;
    int x0 = tx * TILE, y0 = ty * TILE;
    int nx = min(TILE, 100 - x0), ny = min(TILE, 100 - y0);
    int ncols = nx * ny;
    __shared__ float acc[TILE * TILE * CSTR];   // 57,744 B
    __shared__ unsigned int rstart[8];
    __shared__ unsigned int rcum[9];
    int tid = threadIdx.x;
    for (int i = tid; i < ncols * CSTR; i += 256) acc[i] = 0.0f;
    int bxLo = max(x0 - 1, 0), bxHi = min(x0 + nx - 1, 99);
    int byLo = max(y0 - 1, 0), byHi = min(y0 + ny - 1, 99);
    int nbx = bxHi - bxLo + 1;
    if (tid < nbx) {
        int bx = bxLo + tid;
        unsigned int s = offs[b * 10000 + bx * 100 + byLo];
        unsigned int e = offs[b * 10000 + bx * 100 + byHi] + counts[b * 10000 + bx * 100 + byHi];
        rstart[tid] = s;
        rcum[tid + 1] = e - s;
    }
    if (tid == 0) rcum[0] = 0;
    __syncthreads();
    if (tid == 0)
        for (int i = 0; i < nbx; ++i) rcum[i + 1] += rcum[i];
    __syncthreads();
    unsigned int E = rcum[nbx];
    const float* eb = entries + (long long)b * PPB * ESTRIDE;
    int cxMin = max(x0, 1), cyMin = max(y0, 1);   // column 0 never receives weight
    for (unsigned int t = tid; t < E; t += 256) {
        int r = 0;
        while (t >= rcum[r + 1]) ++r;
        const float* ep = eb + (long long)(rstart[r] + (t - rcum[r])) * ESTRIDE;
        float4 e0 = ((const float4*)ep)[0];
        float posx = e0.x, posy = e0.y, posz = e0.z;
        float fz = floorf(posz);
        bool zsem = (posz > 12.0f) && (posz < 35.0f);
        float4 s4[4];
        if (zsem) {
#pragma unroll
            for (int g = 0; g < 4; ++g) s4[g] = ((const float4*)ep)[1 + g];
        }
        float sem[16];
        if (zsem) {
#pragma unroll
            for (int g = 0; g < 4; ++g) {
                sem[4 * g + 0] = s4[g].x; sem[4 * g + 1] = s4[g].y;
                sem[4 * g + 2] = s4[g].z; sem[4 * g + 3] = s4[g].w;
            }
        }
        int fxi = (int)floorf(posx), fyi = (int)floorf(posy);
#pragma unroll
        for (int a = 0; a < 2; ++a) {
            int cx = fxi + a;
            if (cx < cxMin || cx >= x0 + nx) continue;
            float wx = 1.0f - fabsf(posx - (float)cx);
#pragma unroll
            for (int c2 = 0; c2 < 2; ++c2) {
                int cy = fyi + c2;
                if (cy < cyMin || cy >= y0 + ny) continue;
                float wxy = wx * (1.0f - fabsf(posy - (float)cy));
                if (wxy <= 0.0f) continue;
                float* colp = acc + ((cx - x0) * ny + (cy - y0)) * CSTR;
#pragma unroll
                for (int d = 0; d < 2; ++d) {
                    float zf = fz + (float)d;
                    int z = (int)zf;
                    if (z < 1 || z > 47) continue;
                    float w = wxy * (1.0f - fabsf(posz - zf));
                    if (w == 0.0f) continue;
                    atomicAdd(colp + z, w);       // occupancy
                    if (z >= 13 && z < 35) {
                        float* ap = colp + 48 + (z - 13) * 16;
#pragma unroll
                        for (int k = 0; k < 16; ++k)
                            atomicAdd(ap + k, sem[k] * w);
                    }
                }
            }
        }
    }
    __syncthreads();
    // fused rounding + projections; output channel ch stored at smap[b][ch][cy*100+cx]
    float* smb = smap + (long long)b * 19 * 10000;
    for (int o = tid; o < ncols * 19; o += 256) {
        int lc = o / 19, ch = o % 19;
        int cx = x0 + lc / ny, cy = y0 + lc % ny;
        const float* colp = acc + lc * CSTR;
        float s = 0.0f;
        if (ch == 0) {                         // fp_map (MAP_T = 1)
            for (int z = 13; z < 35; ++z) s += rintf(colp[z]);
            s = clamp01(s);
        } else if (ch == 1) {                  // fp_exp (EXP_T = 1)
            for (int z = 0; z < 48; ++z) s += rintf(colp[z]);
            s = clamp01(s);
        } else if (ch == 2) {                  // fp_stair
            for (int z = 20; z < 25; ++z) s += rintf(colp[z]);
            s = clamp01(s);
        } else {                               // cat k (CAT_T = 5)
            int k = ch - 3;
            for (int z = 13; z < 35; ++z) s += rintf(colp[48 + (z - 13) * 16 + k]);
            s = clamp01(s / 5.0f);
        }
        smb[ch * 10000 + cy * 100 + cx] = s;
    }
}

// ---------------- K4: fused rotate+translate grid_sample ----------------
__global__ void k_translate(float* __restrict__ outp,
                            const float* __restrict__ smap,
                            const float* __restrict__ par,
                            float* __restrict__ tstair) {
    int tid = blockIdx.x * blockDim.x + threadIdx.x;
    if (tid >= NBS * NPIX) return;
    int b = tid / NPIX;
    int ij = tid % NPIX;
    int i = ij / NM, j = ij % NM;
    float c = par[b * 4 + 0], s = par[b * 4 + 1];
    float stx = par[b * 4 + 2], sty = par[b * 4 + 3];
    float gx = (((float)j + 0.5f) * 2.0f) / 480.0f - 1.0f;
    float gy = (((float)i + 0.5f) * 2.0f) / 480.0f - 1.0f;
    float px = ((gx + stx) + 1.0f) * 479.0f / 2.0f;
    float py = ((gy + sty) + 1.0f) * 479.0f / 2.0f;
    float x0 = floorf(px), y0 = floorf(py);
    float wx1 = px - x0, wx0 = 1.0f - wx1;
    float wy1 = py - y0, wy0 = 1.0f - wy1;
    int offs[16];
    float wts[16];
    int nt = 0;
#pragma unroll
    for (int t = 0; t < 4; ++t) {  // outer taps in reference gather order
        int ox = t & 1, oy = t >> 1;
        float xo = x0 + (float)ox, yo = y0 + (float)oy;
        if (!(xo >= 0.0f && xo < 480.0f && yo >= 0.0f && yo < 480.0f)) continue;
        float wo = (ox ? wx1 : wx0) * (oy ? wy1 : wy0);
        int ixo = (int)xo, iyo = (int)yo;
        float gx2 = (((float)ixo + 0.5f) * 2.0f) / 480.0f - 1.0f;
        float gy2 = (((float)iyo + 0.5f) * 2.0f) / 480.0f - 1.0f;
        float rx = c * gx2 - s * gy2;
        float ry = s * gx2 + c * gy2;
        float qx = (rx + 1.0f) * 479.0f / 2.0f;
        float qy = (ry + 1.0f) * 479.0f / 2.0f;
        float xq0 = floorf(qx), yq0 = floorf(qy);
        float u1 = qx - xq0, u0 = 1.0f - u1;
        float v1 = qy - yq0, v0 = 1.0f - v1;
#pragma unroll
        for (int t2 = 0; t2 < 4; ++t2) {
            int ax = t2 & 1, ay = t2 >> 1;
            float xa = xq0 + (float)ax, ya = yq0 + (float)ay;
            // agent_view nonzero window: rows [240,340), cols [190,290)
            if (xa >= 190.0f && xa < 290.0f && ya >= 240.0f && ya < 340.0f) {
                float w = wo * ((ax ? u1 : u0) * (ay ? v1 : v0));
                if (w != 0.0f) {
                    offs[nt] = ((int)ya - 240) * 100 + ((int)xa - 190);
                    wts[nt] = w;
                    ++nt;
                }
            }
        }
    }
    float* To = outp + T_OFF;
    long long obase = (long long)b * NC * NPIX + ij;
    if (nt == 0) {  // fast path: entirely outside agent-view support
#pragma unroll
        for (int ch = 0; ch < NC; ++ch) To[obase + (long long)ch * NPIX] = 0.0f;
        tstair[(long long)b * NPIX + ij] = 0.0f;
        return;
    }
    const float* sm = smap + (long long)b * 19 * 10000;
    float a0 = 0.0f, a1 = 0.0f, as_ = 0.0f;
    float cat[16];
#pragma unroll
    for (int k = 0; k < 16; ++k) cat[k] = 0.0f;
    for (int t = 0; t < nt; ++t) {
        float w = wts[t];
        int o = offs[t];
        a0 += w * sm[o];
        a1 += w * sm[10000 + o];
        as_ += w * sm[20000 + o];
#pragma unroll
        for (int k = 0; k < 16; ++k) cat[k] += w * sm[(3 + k) * 10000 + o];
    }
    To[obase] = a0;
    To[obase + (long long)NPIX] = a1;
    To[obase + 2LL * NPIX] = 0.0f;
    To[obase + 3LL * NPIX] = 0.0f;
#pragma unroll
    for (int k = 0; k < 16; ++k) To[obase + (long long)(4 + k) * NPIX] = cat[k];
    tstair[(long long)b * NPIX + ij] = as_;
}

// ---------------- K5: map_pred_stair (writes full S region) ----------------
__global__ void k_stair(const float* __restrict__ T, const float* __restrict__ tstair,
                        const float* __restrict__ par, const float* __restrict__ maps_last,
                        const float* __restrict__ eve, float* __restrict__ outS) {
    int tid = blockIdx.x * blockDim.x + threadIdx.x;
    if (tid >= NBS * NPIX) return;
    int b = tid / NPIX;
    int ij = tid % NPIX;
    int i = ij / NM, j = ij % NM;
    bool eve0 = (eve[b] == 0.0f);
    const float* Tb = T + (long long)b * NC * NPIX;
    float ts0 = tstair[(long long)b * NPIX + ij];
    float t1 = Tb[(long long)NPIX + ij];
    if (b == 0) {
        float dy = (float)i - par[32] + 0.5f;
        float dx = (float)j - par[33] + 0.5f;
        float mask = (dy * dy + dx * dx <= 900.0f) ? 1.0f : 0.0f;
        ts0 *= mask;
        t1 *= mask;
    }
    bool flag = (t1 - ts0) > 0.8f;
    const float* ml = maps_last + (long long)b * NC * NPIX;
    long long obase = (long long)b * NC * NPIX + ij;
#pragma unroll
    for (int ch = 0; ch < NC; ++ch) {
        float tch = (ch == 0) ? ts0 : (ch == 1) ? t1 : Tb[(long long)ch * NPIX + ij];
        float m3 = fmaxf(ml[(long long)ch * NPIX + ij], tch);
        outS[obase + (long long)ch * NPIX] = (ch == 0 && eve0 && flag) ? 0.0f : m3;
    }
}

// ---------------- K6: map_pred (writes full P region) ----------------
__global__ void k_pred(const float* __restrict__ T, const float* __restrict__ maps_last,
                       const float* __restrict__ eve, float* __restrict__ outP) {
    int tid = blockIdx.x * blockDim.x + threadIdx.x;
    if (tid >= NBS * NPIX) return;
    int b = tid / NPIX;
    int ij = tid % NPIX;
    int i = ij / NM, j = ij % NM;
    const float* Tb = T + (long long)b * NC * NPIX;
    float mp = -INFINITY;  // maxpool3 with -inf padding == max over in-bounds nbrs
#pragma unroll
    for (int di = -1; di <= 1; ++di) {
        int ii = i + di;
        if (ii < 0 || ii >= NM) continue;
#pragma unroll
        for (int dj = -1; dj <= 1; ++dj) {
            int jj = j + dj;
            if (jj < 0 || jj >= NM) continue;
            mp = fmaxf(mp, Tb[(long long)ii * NM + jj]);
        }
    }
    float t1 = Tb[(long long)NPIX + ij];
    bool flag = (t1 - mp) > 0.8f;
    bool eve0 = (eve[b] == 0.0f);
    const float* ml = maps_last + (long long)b * NC * NPIX;
    long long obase = (long long)b * NC * NPIX + ij;
#pragma unroll
    for (int ch = 0; ch < NC; ++ch) {
        float m2 = fmaxf(ml[(long long)ch * NPIX + ij], Tb[(long long)ch * NPIX + ij]);
        outP[obase + (long long)ch * NPIX] = (ch == 0 && eve0 && flag) ? 0.0f : m2;
    }
}

extern "C" void kernel_launch(void* const* d_in, const int* in_sizes, int n_in,
                              void* d_out, int out_size, void* d_ws, size_t ws_size,
                              hipStream_t stream) {
    const float* obs = (const float*)d_in[0];
    const float* pose_obs = (const float*)d_in[1];
    const float* maps_last = (const float*)d_in[2];
    const float* poses_last = (const float*)d_in[3];
    const float* eve = (const float*)d_in[4];
    float* outp = (float*)d_out;

    // host-side exact camera focal constant (matches np.float64 -> f32)
    float camf = (float)(320.0 / tan(39.5 * M_PI / 180.0));

    unsigned int* counts = (unsigned int*)(outp + CNT_OFF);
    unsigned int* offs2  = (unsigned int*)(outp + OFF2_OFF);
    unsigned int* curs   = (unsigned int*)(outp + CUR_OFF);
    float4* rec     = (float4*)(outp + REC_OFF);
    float*  entries = outp + ENT_OFF;

    // zero only the 320 KB bucket counters
    hipMemsetAsync(counts, 0, 80000 * sizeof(unsigned int), stream);

    k_pose<<<1, 64, 0, stream>>>(pose_obs, poses_last, outp);

    k_count<<<NPIXELS / 256, 256, 0, stream>>>(obs, eve, camf, counts, rec);

    k_scan<<<NBS, 1024, 0, stream>>>(counts, offs2, curs);

    k_fill<<<NPIXELS / 256, 256, 0, stream>>>(obs, rec, curs, entries);

    k_accum<<<NBS * NTILE * NTILE, 256, 0, stream>>>(entries, counts, offs2,
                                                     outp + SMAP_OFF);

    k_translate<<<(NBS * NPIX) / 256, 256, 0, stream>>>(outp, outp + SMAP_OFF,
                                                        outp + PAR_OFF, outp + TS_OFF);

    k_stair<<<(NBS * NPIX) / 256, 256, 0, stream>>>(outp + T_OFF, outp + TS_OFF,
                                                    outp + PAR_OFF, maps_last, eve,
                                                    outp + S_OFF);

    k_pred<<<(NBS * NPIX) / 256, 256, 0, stream>>>(outp + T_OFF, maps_last, eve,
                                                   outp + P_OFF);
}

// Round 3
// 1202.612 us; speedup vs baseline: 1.2287x; 1.2287x over previous
//
#include <hip/hip_runtime.h>
#include <cmath>

// ---- problem constants ----
#define NBS 8
#define NC 20
#define NFH 480
#define NFW 640
#define NHS 240
#define NWS 320
#define NM 480
#define NPIX (NM * NM)   // 230400
#define NVR 100
#define NPIXELS (NBS * NHS * NWS)  // 614400
#define PPB (NHS * NWS)            // 76800 pixels per batch
#define CPB 4                      // columns (waves) per block in k_accum

// ---- d_out layout (float element offsets) ----
// out = [translated (8,20,480,480) | map_pred | map_pred_stair | poses (8,3)]
constexpr long long T_OFF    = 0LL;
constexpr long long P_OFF    = 36864000LL;   // 8*20*230400
constexpr long long S_OFF    = 73728000LL;
constexpr long long POSE_OFF = 110592000LL;

// scratch lives in the P region (dead until k_pred, which runs last).
// The fused translate+stair kernel writes T and S only -> scratch safe.
constexpr long long SMAP_OFF = P_OFF;                     // 8*19*10000
constexpr long long PAR_OFF  = SMAP_OFF + 1520000LL;      // 64 floats
constexpr long long REC_OFF  = PAR_OFF + 64LL;            // 614400 float4 (by tid)
constexpr long long EPOS_OFF = REC_OFF + 2457600LL;       // 614400 float4 (by slot)
constexpr long long ESEM_OFF = EPOS_OFF + 2457600LL;      // 614400 * 16 sem (by slot)
constexpr long long CNT_OFF  = ESEM_OFF + 9830400LL;      // 80000 u32 counts
constexpr long long OFF2_OFF = CNT_OFF + 80000LL;         // 80000 u32 offsets
constexpr long long CUR_OFF  = OFF2_OFF + 80000LL;        // 80000 u32 cursors
// end = P_OFF + 16,505,664 < P_OFF + 36,864,000  OK

__device__ __forceinline__ float clamp01(float x) {
    return fminf(fmaxf(x, 0.0f), 1.0f);
}

// shared projection math: single source of truth for pos/alive
__device__ __forceinline__ void project_px(const float* __restrict__ ob, float ev,
                                           float camf, int iy, int ix,
                                           float& posx, float& posy, float& posz,
                                           bool& alive, bool& semz) {
    float depth = ob[(3LL * NFH + 2 * iy) * NFW + 2 * ix];
    float th = ev * 0.017453292519943295f;
    float ct = cosf(th), st = sinf(th);
    float X = ((float)(2 * ix) - 319.5f) * depth / camf;
    float Z = ((float)(479 - 2 * iy) - 239.5f) * depth / camf;
    float Yr = ct * depth - st * Z;
    float Zr = st * depth + ct * Z + 88.0f;
    float Xs = X + 250.0f;
    float cx = ((Xs / 5.0f) - 50.0f) / 100.0f * 2.0f;
    float cy = ((Yr / 5.0f) - 50.0f) / 100.0f * 2.0f;
    float cz = ((Zr / 5.0f) - 16.0f) / 48.0f * 2.0f;
    posx = (cx * 100.0f) / 2.0f + 50.0f;
    posy = (cy * 100.0f) / 2.0f + 50.0f;
    posz = (cz * 48.0f) / 2.0f + 24.0f;
    alive = (posx > 0.0f) && (posx < 100.0f) &&
            (posy > 0.0f) && (posy < 100.0f) &&
            (posz > 0.0f) && (posz < 48.0f);
    semz = (posz > 12.0f) && (posz < 35.0f);
}

// ---------------- K1: poses + affine params ----------------
__global__ void k_pose(const float* __restrict__ pose_obs,
                       const float* __restrict__ poses_last,
                       float* __restrict__ outp) {
    int b = threadIdx.x;
    if (b >= NBS) return;
    float* pose_out = outp + POSE_OFF;
    float* par = outp + PAR_OFF;
    const float DEGf = 57.29577951308232f;
    float tr = poses_last[b * 3 + 2] / DEGf;
    float s_tr = sinf(tr), c_tr = cosf(tr);
    float ny = poses_last[b * 3 + 1] + pose_obs[b * 3 + 0] * s_tr + pose_obs[b * 3 + 1] * c_tr;
    float nx = poses_last[b * 3 + 0] + pose_obs[b * 3 + 0] * c_tr - pose_obs[b * 3 + 1] * s_tr;
    float no = poses_last[b * 3 + 2] + pose_obs[b * 3 + 2] * DEGf;
    no = fmodf(no - 180.0f, 360.0f) + 180.0f;
    no = fmodf(no + 180.0f, 360.0f) - 180.0f;
    pose_out[b * 3 + 0] = nx;
    pose_out[b * 3 + 1] = ny;
    pose_out[b * 3 + 2] = no;
    float stx = -((nx * 100.0f) / 5.0f - 240.0f) / 240.0f;
    float sty = -((ny * 100.0f) / 5.0f - 240.0f) / 240.0f;
    float stt = ((90.0f - no) * 3.14159265358979323846f) / 180.0f;
    par[b * 4 + 0] = cosf(stt);
    par[b * 4 + 1] = sinf(stt);
    par[b * 4 + 2] = stx;
    par[b * 4 + 3] = sty;
    if (b == 0) {
        int sy = (int)((ny * 100.0f) / 5.0f);   // truncation matches astype(int32)
        int sx = (int)((nx * 100.0f) / 5.0f);
        sy = min(max(sy, 30), NM - 31);
        sx = min(max(sx, 30), NM - 31);
        par[32] = (float)sy;
        par[33] = (float)sx;
    }
}

// ---------------- K2a: project pixels, write rec, count per bucket ----------------
__global__ void k_count(const float* __restrict__ obs,
                        const float* __restrict__ eve, float camf,
                        unsigned int* __restrict__ counts,
                        float4* __restrict__ rec) {
    int tid = blockIdx.x * blockDim.x + threadIdx.x;
    if (tid >= NPIXELS) return;
    int b = tid / PPB;
    int p = tid % PPB;
    int iy = p / NWS, ix = p % NWS;
    const float* ob = obs + (long long)b * NC * NFH * NFW;
    float posx, posy, posz;
    bool alive, semz;
    project_px(ob, eve[b], camf, iy, ix, posx, posy, posz, alive, semz);
    float flag = alive ? (semz ? 2.0f : 1.0f) : 0.0f;
    rec[tid] = make_float4(posx, posy, posz, flag);
    if (!alive) return;
    int fx = (int)floorf(posx);   // in [0,99]
    int fy = (int)floorf(posy);
    atomicAdd(&counts[b * 10000 + fx * 100 + fy], 1u);
}

// ---------------- K2b: per-batch exclusive prefix sum (single-pass block scan) ----------------
__global__ void __launch_bounds__(1024) k_scan(const unsigned int* __restrict__ counts,
                                               unsigned int* __restrict__ offs,
                                               unsigned int* __restrict__ curs) {
    int b = blockIdx.x;          // 8 blocks
    int t = threadIdx.x;         // 1024
    int lane = t & 63, wid = t >> 6;
    const unsigned int* cb = counts + b * 10000;
    unsigned int base_i = (unsigned int)t * 10u;
    unsigned int v[10];
    unsigned int s = 0;
#pragma unroll
    for (int k = 0; k < 10; ++k) {
        unsigned int i = base_i + (unsigned int)k;
        unsigned int x = (i < 10000u) ? cb[i] : 0u;
        v[k] = s;                // exclusive within thread
        s += x;
    }
    unsigned int incl = s;
#pragma unroll
    for (int d = 1; d < 64; d <<= 1) {
        unsigned int u = __shfl_up(incl, d);
        if (lane >= d) incl += u;
    }
    __shared__ unsigned int wtot[16];
    __shared__ unsigned int wexc[16];
    if (lane == 63) wtot[wid] = incl;
    __syncthreads();
    if (t == 0) {
        unsigned int a = 0;
        for (int i = 0; i < 16; ++i) { wexc[i] = a; a += wtot[i]; }
    }
    __syncthreads();
    unsigned int tbase = wexc[wid] + (incl - s);
#pragma unroll
    for (int k = 0; k < 10; ++k) {
        unsigned int i = base_i + (unsigned int)k;
        if (i < 10000u) {
            unsigned int e = tbase + v[k];
            offs[b * 10000 + i] = e;
            curs[b * 10000 + i] = e;
        }
    }
}

// ---------------- K2c: fill SoA bucket entries (pos float4 + 16-float sem) ----------------
__global__ void k_fill(const float* __restrict__ obs,
                       const float4* __restrict__ rec,
                       unsigned int* __restrict__ curs,
                       float4* __restrict__ epos,
                       float4* __restrict__ esem4) {
    int tid = blockIdx.x * blockDim.x + threadIdx.x;
    if (tid >= NPIXELS) return;
    float4 r = rec[tid];
    if (r.w == 0.0f) return;
    int b = tid / PPB;
    int p = tid % PPB;
    int iy = p / NWS, ix = p % NWS;
    int fx = (int)floorf(r.x);
    int fy = (int)floorf(r.y);
    unsigned int slot = atomicAdd(&curs[b * 10000 + fx * 100 + fy], 1u);
    long long gslot = (long long)b * PPB + slot;
    epos[gslot] = make_float4(r.x, r.y, r.z, 0.0f);
    if (r.w == 2.0f) {  // sem needed: 2x2 mean pool of channels 4..19
        const float* ob = obs + (long long)b * NC * NFH * NFW;
        float sem[16];
#pragma unroll
        for (int k = 0; k < 16; ++k) {
            const float* q = ob + ((long long)(4 + k) * NFH + 2 * iy) * NFW + 2 * ix;
            sem[k] = (q[0] + q[1] + q[NFW] + q[NFW + 1]) * 0.25f;
        }
#pragma unroll
        for (int g = 0; g < 4; ++g)
            esem4[gslot * 4 + g] =
                make_float4(sem[4 * g], sem[4 * g + 1], sem[4 * g + 2], sem[4 * g + 3]);
    }
}

// ---------------- K2d: per-column wave gather-accumulate + fused z-projection ----------------
// 4 independent waves per block, one voxel column each. Entries of the 4 halo
// buckets form 2 contiguous ranges (bx = x-1, x ; by in {y-1,y}). LDS 400-float
// accumulator per wave; SoA coalesced entry reads (no random gathers).
__global__ void __launch_bounds__(256) k_accum(const float4* __restrict__ epos,
                                               const float4* __restrict__ esem4,
                                               const unsigned int* __restrict__ counts,
                                               const unsigned int* __restrict__ offs,
                                               float* __restrict__ smap) {
    int wid = threadIdx.x >> 6, lane = threadIdx.x & 63;
    int col = blockIdx.x * CPB + wid;     // 0..79999
    int b = col / 10000;
    int xy = col % 10000;
    int x = xy / 100, y = xy % 100;
    __shared__ float acc[CPB][400];
    float* A = acc[wid];
    for (int i = lane; i < 400; i += 64) A[i] = 0.0f;
    __syncthreads();
    if (x >= 1 && y >= 1) {               // column x==0 / y==0 never receives weight
        int base = b * 10000;
        int b00 = base + (x - 1) * 100 + (y - 1);
        int b01 = base + (x - 1) * 100 + y;
        int b10 = base + x * 100 + (y - 1);
        int b11 = base + x * 100 + y;
        unsigned int s0 = offs[b00];
        unsigned int n0 = offs[b01] + counts[b01] - s0;
        unsigned int s1 = offs[b10];
        unsigned int n1 = offs[b11] + counts[b11] - s1;
        unsigned int E = n0 + n1;
        const float4* pb = epos + (long long)b * PPB;
        const float4* sb = esem4 + (long long)b * PPB * 4;
        float fx_ = (float)x, fy_ = (float)y;
        for (unsigned int t = lane; t < E; t += 64) {
            unsigned int idx = (t < n0) ? (s0 + t) : (s1 + (t - n0));
            float4 e = pb[idx];
            float wx = 1.0f - fabsf(e.x - fx_);
            float wy = 1.0f - fabsf(e.y - fy_);
            float wxy = wx * wy;
            if (wxy <= 0.0f) continue;
            float posz = e.z;
            float fz = floorf(posz);
            bool zsem = (posz > 12.0f) && (posz < 35.0f);
            float sem[16];
            if (zsem) {
#pragma unroll
                for (int g = 0; g < 4; ++g) {
                    float4 s4 = sb[(long long)idx * 4 + g];
                    sem[4 * g + 0] = s4.x; sem[4 * g + 1] = s4.y;
                    sem[4 * g + 2] = s4.z; sem[4 * g + 3] = s4.w;
                }
            }
#pragma unroll
            for (int d = 0; d < 2; ++d) {
                float zf = fz + (float)d;
                int z = (int)zf;
                if (z < 1 || z > 47) continue;
                float w = wxy * (1.0f - fabsf(posz - zf));
                if (w == 0.0f) continue;
                atomicAdd(&A[z], w);          // occupancy
                if (z >= 13 && z < 35) {
                    float* ap = A + 48 + (z - 13) * 16;
#pragma unroll
                    for (int k = 0; k < 16; ++k)
                        atomicAdd(ap + k, sem[k] * w);
                }
            }
        }
    }
    __syncthreads();
    // fused rounding + projections; smap[b][ch][y*100+x]
    float* smb = smap + (long long)b * 19 * 10000;
    int ij = y * 100 + x;
    if (lane < 16) {
        float s = 0.0f;
#pragma unroll
        for (int z = 13; z < 35; ++z) s += rintf(A[48 + (z - 13) * 16 + lane]);
        smb[(3 + lane) * 10000 + ij] = clamp01(s / 5.0f);   // CAT_T = 5
    } else if (lane == 16) {
        float s = 0.0f;
        for (int z = 13; z < 35; ++z) s += rintf(A[z]);
        smb[ij] = clamp01(s);                               // fp_map (MAP_T = 1)
    } else if (lane == 17) {
        float s = 0.0f;
        for (int z = 0; z < 48; ++z) s += rintf(A[z]);
        smb[10000 + ij] = clamp01(s);                       // fp_exp (EXP_T = 1)
    } else if (lane == 18) {
        float s = 0.0f;
        for (int z = 20; z < 25; ++z) s += rintf(A[z]);
        smb[20000 + ij] = clamp01(s);                       // fp_stair
    }
}

// ---------------- K4: fused rotate+translate grid_sample + map_pred_stair ----------------
// translated_stair differs from translated only in ch0 (fp_stair) and the b==0
// circle mask on ch0/ch1 -> S output computed from the same register values.
__global__ void k_translate(float* __restrict__ outp,
                            const float* __restrict__ smap,
                            const float* __restrict__ par,
                            const float* __restrict__ maps_last,
                            const float* __restrict__ eve) {
    int tid = blockIdx.x * blockDim.x + threadIdx.x;
    if (tid >= NBS * NPIX) return;
    int b = tid / NPIX;
    int ij = tid % NPIX;
    int i = ij / NM, j = ij % NM;
    float c = par[b * 4 + 0], s = par[b * 4 + 1];
    float stx = par[b * 4 + 2], sty = par[b * 4 + 3];
    float gx = (((float)j + 0.5f) * 2.0f) / 480.0f - 1.0f;
    float gy = (((float)i + 0.5f) * 2.0f) / 480.0f - 1.0f;
    float px = ((gx + stx) + 1.0f) * 479.0f / 2.0f;
    float py = ((gy + sty) + 1.0f) * 479.0f / 2.0f;
    float x0 = floorf(px), y0 = floorf(py);
    float wx1 = px - x0, wx0 = 1.0f - wx1;
    float wy1 = py - y0, wy0 = 1.0f - wy1;
    int offs[16];
    float wts[16];
    int nt = 0;
#pragma unroll
    for (int t = 0; t < 4; ++t) {  // outer taps in reference gather order
        int ox = t & 1, oy = t >> 1;
        float xo = x0 + (float)ox, yo = y0 + (float)oy;
        if (!(xo >= 0.0f && xo < 480.0f && yo >= 0.0f && yo < 480.0f)) continue;
        float wo = (ox ? wx1 : wx0) * (oy ? wy1 : wy0);
        int ixo = (int)xo, iyo = (int)yo;
        float gx2 = (((float)ixo + 0.5f) * 2.0f) / 480.0f - 1.0f;
        float gy2 = (((float)iyo + 0.5f) * 2.0f) / 480.0f - 1.0f;
        float rx = c * gx2 - s * gy2;
        float ry = s * gx2 + c * gy2;
        float qx = (rx + 1.0f) * 479.0f / 2.0f;
        float qy = (ry + 1.0f) * 479.0f / 2.0f;
        float xq0 = floorf(qx), yq0 = floorf(qy);
        float u1 = qx - xq0, u0 = 1.0f - u1;
        float v1 = qy - yq0, v0 = 1.0f - v1;
#pragma unroll
        for (int t2 = 0; t2 < 4; ++t2) {
            int ax = t2 & 1, ay = t2 >> 1;
            float xa = xq0 + (float)ax, ya = yq0 + (float)ay;
            // agent_view nonzero window: rows [240,340), cols [190,290)
            if (xa >= 190.0f && xa < 290.0f && ya >= 240.0f && ya < 340.0f) {
                float w = wo * ((ax ? u1 : u0) * (ay ? v1 : v0));
                if (w != 0.0f) {
                    offs[nt] = ((int)ya - 240) * 100 + ((int)xa - 190);
                    wts[nt] = w;
                    ++nt;
                }
            }
        }
    }
    float a0 = 0.0f, a1 = 0.0f, as_ = 0.0f;
    float cat[16];
#pragma unroll
    for (int k = 0; k < 16; ++k) cat[k] = 0.0f;
    if (nt > 0) {
        const float* sm = smap + (long long)b * 19 * 10000;
        for (int t = 0; t < nt; ++t) {
            float w = wts[t];
            int o = offs[t];
            a0 += w * sm[o];
            a1 += w * sm[10000 + o];
            as_ += w * sm[20000 + o];
#pragma unroll
            for (int k = 0; k < 16; ++k) cat[k] += w * sm[(3 + k) * 10000 + o];
        }
    }
    // ---- write translated (T) ----
    float* To = outp + T_OFF;
    long long obase = (long long)b * NC * NPIX + ij;
    To[obase] = a0;
    To[obase + (long long)NPIX] = a1;
    To[obase + 2LL * NPIX] = 0.0f;
    To[obase + 3LL * NPIX] = 0.0f;
#pragma unroll
    for (int k = 0; k < 16; ++k) To[obase + (long long)(4 + k) * NPIX] = cat[k];
    // ---- fused map_pred_stair (S) ----
    float ts0 = as_, t1s = a1;
    if (b == 0) {
        float dy = (float)i - par[32] + 0.5f;
        float dx = (float)j - par[33] + 0.5f;
        float mask = (dy * dy + dx * dx <= 900.0f) ? 1.0f : 0.0f;
        ts0 *= mask;
        t1s *= mask;
    }
    bool eve0 = (eve[b] == 0.0f);
    bool flag = (t1s - ts0) > 0.8f;
    const float* ml = maps_last + (long long)b * NC * NPIX;
    float* So = outp + S_OFF;
#pragma unroll
    for (int ch = 0; ch < NC; ++ch) {
        float tch = (ch == 0) ? ts0 : (ch == 1) ? t1s
                  : (ch < 4) ? 0.0f : cat[ch - 4];
        float m3 = fmaxf(ml[(long long)ch * NPIX + ij], tch);
        So[obase + (long long)ch * NPIX] = (ch == 0 && eve0 && flag) ? 0.0f : m3;
    }
}

// ---------------- K6: map_pred (writes full P region) ----------------
__global__ void k_pred(const float* __restrict__ T, const float* __restrict__ maps_last,
                       const float* __restrict__ eve, float* __restrict__ outP) {
    int tid = blockIdx.x * blockDim.x + threadIdx.x;
    if (tid >= NBS * NPIX) return;
    int b = tid / NPIX;
    int ij = tid % NPIX;
    int i = ij / NM, j = ij % NM;
    const float* Tb = T + (long long)b * NC * NPIX;
    float mp = -INFINITY;  // maxpool3 with -inf padding == max over in-bounds nbrs
#pragma unroll
    for (int di = -1; di <= 1; ++di) {
        int ii = i + di;
        if (ii < 0 || ii >= NM) continue;
#pragma unroll
        for (int dj = -1; dj <= 1; ++dj) {
            int jj = j + dj;
            if (jj < 0 || jj >= NM) continue;
            mp = fmaxf(mp, Tb[(long long)ii * NM + jj]);
        }
    }
    float t1 = Tb[(long long)NPIX + ij];
    bool flag = (t1 - mp) > 0.8f;
    bool eve0 = (eve[b] == 0.0f);
    const float* ml = maps_last + (long long)b * NC * NPIX;
    long long obase = (long long)b * NC * NPIX + ij;
#pragma unroll
    for (int ch = 0; ch < NC; ++ch) {
        float m2 = fmaxf(ml[(long long)ch * NPIX + ij], Tb[(long long)ch * NPIX + ij]);
        outP[obase + (long long)ch * NPIX] = (ch == 0 && eve0 && flag) ? 0.0f : m2;
    }
}

extern "C" void kernel_launch(void* const* d_in, const int* in_sizes, int n_in,
                              void* d_out, int out_size, void* d_ws, size_t ws_size,
                              hipStream_t stream) {
    const float* obs = (const float*)d_in[0];
    const float* pose_obs = (const float*)d_in[1];
    const float* maps_last = (const float*)d_in[2];
    const float* poses_last = (const float*)d_in[3];
    const float* eve = (const float*)d_in[4];
    float* outp = (float*)d_out;

    // host-side exact camera focal constant (matches np.float64 -> f32)
    float camf = (float)(320.0 / tan(39.5 * M_PI / 180.0));

    unsigned int* counts = (unsigned int*)(outp + CNT_OFF);
    unsigned int* offs2  = (unsigned int*)(outp + OFF2_OFF);
    unsigned int* curs   = (unsigned int*)(outp + CUR_OFF);
    float4* rec   = (float4*)(outp + REC_OFF);
    float4* epos  = (float4*)(outp + EPOS_OFF);
    float4* esem4 = (float4*)(outp + ESEM_OFF);

    // zero only the 320 KB bucket counters
    hipMemsetAsync(counts, 0, 80000 * sizeof(unsigned int), stream);

    k_pose<<<1, 64, 0, stream>>>(pose_obs, poses_last, outp);

    k_count<<<NPIXELS / 256, 256, 0, stream>>>(obs, eve, camf, counts, rec);

    k_scan<<<NBS, 1024, 0, stream>>>(counts, offs2, curs);

    k_fill<<<NPIXELS / 256, 256, 0, stream>>>(obs, rec, curs, epos, esem4);

    k_accum<<<(NBS * 10000) / CPB, 256, 0, stream>>>(epos, esem4, counts, offs2,
                                                     outp + SMAP_OFF);

    k_translate<<<(NBS * NPIX) / 256, 256, 0, stream>>>(outp, outp + SMAP_OFF,
                                                        outp + PAR_OFF, maps_last, eve);

    k_pred<<<(NBS * NPIX) / 256, 256, 0, stream>>>(outp + T_OFF, maps_last, eve,
                                                   outp + P_OFF);
}

// Round 4
// 1128.938 us; speedup vs baseline: 1.3089x; 1.0653x over previous
//
#include <hip/hip_runtime.h>
#include <cmath>

// ---- problem constants ----
#define NBS 8
#define NC 20
#define NFH 480
#define NFW 640
#define NHS 240
#define NWS 320
#define NM 480
#define NPIX (NM * NM)   // 230400
#define NPIXELS (NBS * NHS * NWS)  // 614400
#define PPB (NHS * NWS)            // 76800 pixels per batch
#define YW 20                      // y-chunk width in k_accum

// ---- d_out layout (float element offsets) ----
// out = [translated (8,20,480,480) | map_pred | map_pred_stair | poses (8,3)]
constexpr long long T_OFF    = 0LL;
constexpr long long P_OFF    = 36864000LL;   // 8*20*230400
constexpr long long S_OFF    = 73728000LL;
constexpr long long POSE_OFF = 110592000LL;

// ---- scratch layout (float offsets relative to scratch base) ----
// Primary: scratch in d_ws (allows fusing map_pred -> no kernel touches scratch
// after it's dead). Fallback (ws too small): scratch in P region, separate k_pred.
constexpr long long SMAP_O = 0LL;                  // 8*10000*20 floats, [ij][20]
constexpr long long PAR_O  = SMAP_O + 1600000LL;   // 64 floats
constexpr long long REC_O  = PAR_O + 64LL;         // 614400 float4 (by tid)
constexpr long long EPOS_O = REC_O + 2457600LL;    // 614400 float4 (by slot)
constexpr long long ESEM_O = EPOS_O + 2457600LL;   // 614400*16 sem (by slot)
constexpr long long CNT_O  = ESEM_O + 9830400LL;   // 80000 u32 counts
constexpr long long OFF_O  = CNT_O + 80000LL;      // 80000 u32 offsets
constexpr long long CUR_O  = OFF_O + 80000LL;      // 80000 u32 cursors
constexpr long long SCR_END = CUR_O + 80000LL;     // 16,585,664 floats = 66.3 MB
// fallback fits: SCR_END < 36,864,000 (P region)  OK

__device__ __forceinline__ float clamp01(float x) {
    return fminf(fmaxf(x, 0.0f), 1.0f);
}

// shared projection math: single source of truth for pos/alive
__device__ __forceinline__ void project_px(const float* __restrict__ ob, float ev,
                                           float camf, int iy, int ix,
                                           float& posx, float& posy, float& posz,
                                           bool& alive, bool& semz) {
    float depth = ob[(3LL * NFH + 2 * iy) * NFW + 2 * ix];
    float th = ev * 0.017453292519943295f;
    float ct = cosf(th), st = sinf(th);
    float X = ((float)(2 * ix) - 319.5f) * depth / camf;
    float Z = ((float)(479 - 2 * iy) - 239.5f) * depth / camf;
    float Yr = ct * depth - st * Z;
    float Zr = st * depth + ct * Z + 88.0f;
    float Xs = X + 250.0f;
    float cx = ((Xs / 5.0f) - 50.0f) / 100.0f * 2.0f;
    float cy = ((Yr / 5.0f) - 50.0f) / 100.0f * 2.0f;
    float cz = ((Zr / 5.0f) - 16.0f) / 48.0f * 2.0f;
    posx = (cx * 100.0f) / 2.0f + 50.0f;
    posy = (cy * 100.0f) / 2.0f + 50.0f;
    posz = (cz * 48.0f) / 2.0f + 24.0f;
    alive = (posx > 0.0f) && (posx < 100.0f) &&
            (posy > 0.0f) && (posy < 100.0f) &&
            (posz > 0.0f) && (posz < 48.0f);
    semz = (posz > 12.0f) && (posz < 35.0f);
}

// ---------------- K1: poses + affine params ----------------
__global__ void k_pose(const float* __restrict__ pose_obs,
                       const float* __restrict__ poses_last,
                       float* __restrict__ pose_out,
                       float* __restrict__ par) {
    int b = threadIdx.x;
    if (b >= NBS) return;
    const float DEGf = 57.29577951308232f;
    float tr = poses_last[b * 3 + 2] / DEGf;
    float s_tr = sinf(tr), c_tr = cosf(tr);
    float ny = poses_last[b * 3 + 1] + pose_obs[b * 3 + 0] * s_tr + pose_obs[b * 3 + 1] * c_tr;
    float nx = poses_last[b * 3 + 0] + pose_obs[b * 3 + 0] * c_tr - pose_obs[b * 3 + 1] * s_tr;
    float no = poses_last[b * 3 + 2] + pose_obs[b * 3 + 2] * DEGf;
    no = fmodf(no - 180.0f, 360.0f) + 180.0f;
    no = fmodf(no + 180.0f, 360.0f) - 180.0f;
    pose_out[b * 3 + 0] = nx;
    pose_out[b * 3 + 1] = ny;
    pose_out[b * 3 + 2] = no;
    float stx = -((nx * 100.0f) / 5.0f - 240.0f) / 240.0f;
    float sty = -((ny * 100.0f) / 5.0f - 240.0f) / 240.0f;
    float stt = ((90.0f - no) * 3.14159265358979323846f) / 180.0f;
    par[b * 4 + 0] = cosf(stt);
    par[b * 4 + 1] = sinf(stt);
    par[b * 4 + 2] = stx;
    par[b * 4 + 3] = sty;
    if (b == 0) {
        int sy = (int)((ny * 100.0f) / 5.0f);   // truncation matches astype(int32)
        int sx = (int)((nx * 100.0f) / 5.0f);
        sy = min(max(sy, 30), NM - 31);
        sx = min(max(sx, 30), NM - 31);
        par[32] = (float)sy;
        par[33] = (float)sx;
    }
}

// ---------------- K2a: project pixels, write rec, count per bucket ----------------
__global__ void k_count(const float* __restrict__ obs,
                        const float* __restrict__ eve, float camf,
                        unsigned int* __restrict__ counts,
                        float4* __restrict__ rec) {
    int tid = blockIdx.x * blockDim.x + threadIdx.x;
    if (tid >= NPIXELS) return;
    int b = tid / PPB;
    int p = tid % PPB;
    int iy = p / NWS, ix = p % NWS;
    const float* ob = obs + (long long)b * NC * NFH * NFW;
    float posx, posy, posz;
    bool alive, semz;
    project_px(ob, eve[b], camf, iy, ix, posx, posy, posz, alive, semz);
    float flag = alive ? (semz ? 2.0f : 1.0f) : 0.0f;
    rec[tid] = make_float4(posx, posy, posz, flag);
    if (!alive) return;
    int fx = (int)floorf(posx);   // in [0,99]
    int fy = (int)floorf(posy);
    atomicAdd(&counts[b * 10000 + fx * 100 + fy], 1u);
}

// ---------------- K2b: per-batch exclusive prefix sum (single-pass block scan) ----------------
__global__ void __launch_bounds__(1024) k_scan(const unsigned int* __restrict__ counts,
                                               unsigned int* __restrict__ offs,
                                               unsigned int* __restrict__ curs) {
    int b = blockIdx.x;          // 8 blocks
    int t = threadIdx.x;         // 1024
    int lane = t & 63, wid = t >> 6;
    const unsigned int* cb = counts + b * 10000;
    unsigned int base_i = (unsigned int)t * 10u;
    unsigned int v[10];
    unsigned int s = 0;
#pragma unroll
    for (int k = 0; k < 10; ++k) {
        unsigned int i = base_i + (unsigned int)k;
        unsigned int x = (i < 10000u) ? cb[i] : 0u;
        v[k] = s;                // exclusive within thread
        s += x;
    }
    unsigned int incl = s;
#pragma unroll
    for (int d = 1; d < 64; d <<= 1) {
        unsigned int u = __shfl_up(incl, d);
        if (lane >= d) incl += u;
    }
    __shared__ unsigned int wtot[16];
    __shared__ unsigned int wexc[16];
    if (lane == 63) wtot[wid] = incl;
    __syncthreads();
    if (t == 0) {
        unsigned int a = 0;
        for (int i = 0; i < 16; ++i) { wexc[i] = a; a += wtot[i]; }
    }
    __syncthreads();
    unsigned int tbase = wexc[wid] + (incl - s);
#pragma unroll
    for (int k = 0; k < 10; ++k) {
        unsigned int i = base_i + (unsigned int)k;
        if (i < 10000u) {
            unsigned int e = tbase + v[k];
            offs[b * 10000 + i] = e;
            curs[b * 10000 + i] = e;
        }
    }
}

// ---------------- K2c: fill SoA bucket entries (pos float4 + 16-float sem) ----------------
__global__ void k_fill(const float* __restrict__ obs,
                       const float4* __restrict__ rec,
                       unsigned int* __restrict__ curs,
                       float4* __restrict__ epos,
                       float4* __restrict__ esem4) {
    int tid = blockIdx.x * blockDim.x + threadIdx.x;
    if (tid >= NPIXELS) return;
    float4 r = rec[tid];
    if (r.w == 0.0f) return;
    int b = tid / PPB;
    int p = tid % PPB;
    int iy = p / NWS, ix = p % NWS;
    int fx = (int)floorf(r.x);
    int fy = (int)floorf(r.y);
    unsigned int slot = atomicAdd(&curs[b * 10000 + fx * 100 + fy], 1u);
    long long gslot = (long long)b * PPB + slot;
    epos[gslot] = make_float4(r.x, r.y, r.z, 0.0f);
    if (r.w == 2.0f) {  // sem needed: 2x2 mean pool of channels 4..19
        const float* ob = obs + (long long)b * NC * NFH * NFW;
        float sem[16];
#pragma unroll
        for (int k = 0; k < 16; ++k) {
            const float* q = ob + ((long long)(4 + k) * NFH + 2 * iy) * NFW + 2 * ix;
            sem[k] = (q[0] + q[1] + q[NFW] + q[NFW + 1]) * 0.25f;
        }
#pragma unroll
        for (int g = 0; g < 4; ++g)
            esem4[gslot * 4 + g] =
                make_float4(sem[4 * g], sem[4 * g + 1], sem[4 * g + 2], sem[4 * g + 3]);
    }
}

// ---------------- K2d: strip-tiled gather-accumulate + fused z-projection ----------------
// One 256-thread block per (b, x, y-chunk of YW). Columns (x, y0..y0+YW-1) receive
// weight only from bucket strips fx in {x-1, x} -- two contiguous entry ranges.
// Each entry scatters to its (<=2 y-cols) x (<=2 z) corners via LDS atomics.
// smap layout: [b][cy*100+cx][20] (ch: 0=fp_map 1=fp_exp 2=fp_stair 3..18=cat, 19=pad)
__global__ void __launch_bounds__(256) k_accum(const float4* __restrict__ epos,
                                               const float4* __restrict__ esem4,
                                               const unsigned int* __restrict__ counts,
                                               const unsigned int* __restrict__ offs,
                                               float* __restrict__ smap) {
    int blk = blockIdx.x;              // b*500 + x*5 + yc
    int b = blk / 500;
    int r = blk % 500;
    int x = r / 5;
    int y0 = (r % 5) * YW;
    __shared__ float acc[YW][400];     // 32 KB: [0..48) occ(z), [48+(z-13)*16+k] sem
    int tid = threadIdx.x;
    for (int i2 = tid; i2 < YW * 400; i2 += 256) (&acc[0][0])[i2] = 0.0f;
    __syncthreads();
    if (x >= 1) {                      // column x==0 never receives weight
        int byLo = max(y0 - 1, 0);
        int byHi = min(y0 + YW - 1, 99);
        int base = b * 10000;
        int s0i = base + (x - 1) * 100 + byLo;
        int e0i = base + (x - 1) * 100 + byHi;
        int s1i = base + x * 100 + byLo;
        int e1i = base + x * 100 + byHi;
        unsigned int st0 = offs[s0i];
        unsigned int n0 = offs[e0i] + counts[e0i] - st0;
        unsigned int st1 = offs[s1i];
        unsigned int n1 = offs[e1i] + counts[e1i] - st1;
        unsigned int E = n0 + n1;
        const float4* pb = epos + (long long)b * PPB;
        const float4* sb = esem4 + (long long)b * PPB * 4;
        float xf = (float)x;
        for (unsigned int t = tid; t < E; t += 256) {
            unsigned int idx = (t < n0) ? (st0 + t) : (st1 + (t - n0));
            float4 e = pb[idx];
            float wx = 1.0f - fabsf(e.x - xf);
            if (wx <= 0.0f) continue;
            float posy = e.y, posz = e.z;
            int fyi = (int)floorf(posy);
            float fz = floorf(posz);
            bool zsem = (posz > 12.0f) && (posz < 35.0f);
            float sem[16];
            if (zsem) {
#pragma unroll
                for (int g = 0; g < 4; ++g) {
                    float4 s4 = sb[(long long)idx * 4 + g];
                    sem[4 * g + 0] = s4.x; sem[4 * g + 1] = s4.y;
                    sem[4 * g + 2] = s4.z; sem[4 * g + 3] = s4.w;
                }
            }
#pragma unroll
            for (int dy2 = 0; dy2 < 2; ++dy2) {
                int cy = fyi + dy2;
                if (cy < 1 || cy >= 100 || cy < y0 || cy >= y0 + YW) continue;
                float w2 = wx * (1.0f - fabsf(posy - (float)cy));
                if (w2 <= 0.0f) continue;
                float* A = acc[cy - y0];
#pragma unroll
                for (int d = 0; d < 2; ++d) {
                    float zf = fz + (float)d;
                    int z = (int)zf;
                    if (z < 1 || z > 47) continue;
                    float w = w2 * (1.0f - fabsf(posz - zf));
                    if (w == 0.0f) continue;
                    atomicAdd(&A[z], w);          // occupancy
                    if (z >= 13 && z < 35) {
                        float* ap = A + 48 + (z - 13) * 16;
#pragma unroll
                        for (int k = 0; k < 16; ++k)
                            atomicAdd(ap + k, sem[k] * w);
                    }
                }
            }
        }
    }
    __syncthreads();
    // fused rounding + projections -> interleaved smap [ij][20]
    float* smb = smap + (long long)b * 200000;
    for (int o = tid; o < YW * 20; o += 256) {
        int ly = o / 20, ch = o % 20;
        int cy = y0 + ly;
        const float* A = acc[ly];
        float s = 0.0f;
        if (ch == 0) {                          // fp_map (MAP_T = 1)
            for (int z = 13; z < 35; ++z) s += rintf(A[z]);
            s = clamp01(s);
        } else if (ch == 1) {                   // fp_exp (EXP_T = 1)
            for (int z = 0; z < 48; ++z) s += rintf(A[z]);
            s = clamp01(s);
        } else if (ch == 2) {                   // fp_stair
            for (int z = 20; z < 25; ++z) s += rintf(A[z]);
            s = clamp01(s);
        } else if (ch < 19) {                   // cat k (CAT_T = 5)
            int k = ch - 3;
            for (int z = 13; z < 35; ++z) s += rintf(A[48 + (z - 13) * 16 + k]);
            s = clamp01(s / 5.0f);
        }                                       // ch 19 = pad (0)
        smb[(long long)(cy * 100 + x) * 20 + ch] = s;
    }
}

// ---------------- tap evaluation: rotate+translate double grid_sample ----------------
// FULL: accumulate all 19 channels; else ch0 only. Accumulation order identical in
// both instantiations (tap order), so ch0 values are bit-identical across them.
template<bool FULL>
__device__ __forceinline__ void eval_pix(int i, int j, const float* __restrict__ smb,
                                         float c, float s, float stx, float sty,
                                         float& a0, float& a1, float& as_, float* cat) {
    a0 = 0.0f; a1 = 0.0f; as_ = 0.0f;
    float gx = (((float)j + 0.5f) * 2.0f) / 480.0f - 1.0f;
    float gy = (((float)i + 0.5f) * 2.0f) / 480.0f - 1.0f;
    float px = ((gx + stx) + 1.0f) * 479.0f / 2.0f;
    float py = ((gy + sty) + 1.0f) * 479.0f / 2.0f;
    float x0 = floorf(px), y0 = floorf(py);
    float wx1 = px - x0, wx0 = 1.0f - wx1;
    float wy1 = py - y0, wy0 = 1.0f - wy1;
#pragma unroll
    for (int t = 0; t < 4; ++t) {  // outer taps in reference gather order
        int ox = t & 1, oy = t >> 1;
        float xo = x0 + (float)ox, yo = y0 + (float)oy;
        if (!(xo >= 0.0f && xo < 480.0f && yo >= 0.0f && yo < 480.0f)) continue;
        float wo = (ox ? wx1 : wx0) * (oy ? wy1 : wy0);
        int ixo = (int)xo, iyo = (int)yo;
        float gx2 = (((float)ixo + 0.5f) * 2.0f) / 480.0f - 1.0f;
        float gy2 = (((float)iyo + 0.5f) * 2.0f) / 480.0f - 1.0f;
        float rx = c * gx2 - s * gy2;
        float ry = s * gx2 + c * gy2;
        float qx = (rx + 1.0f) * 479.0f / 2.0f;
        float qy = (ry + 1.0f) * 479.0f / 2.0f;
        float xq0 = floorf(qx), yq0 = floorf(qy);
        float u1 = qx - xq0, u0 = 1.0f - u1;
        float v1 = qy - yq0, v0 = 1.0f - v1;
#pragma unroll
        for (int t2 = 0; t2 < 4; ++t2) {
            int ax = t2 & 1, ay = t2 >> 1;
            float xa = xq0 + (float)ax, ya = yq0 + (float)ay;
            // agent_view nonzero window: rows [240,340), cols [190,290)
            if (xa >= 190.0f && xa < 290.0f && ya >= 240.0f && ya < 340.0f) {
                float w = wo * ((ax ? u1 : u0) * (ay ? v1 : v0));
                if (w != 0.0f) {
                    int o = ((int)ya - 240) * 100 + ((int)xa - 190);
                    const float* bp = smb + (long long)o * 20;
                    if constexpr (FULL) {
                        const float4* b4 = (const float4*)bp;
                        float4 v0_ = b4[0], v1_ = b4[1], v2_ = b4[2], v3_ = b4[3], v4_ = b4[4];
                        a0 += w * v0_.x; a1 += w * v0_.y; as_ += w * v0_.z;
                        cat[0]  += w * v0_.w;
                        cat[1]  += w * v1_.x; cat[2]  += w * v1_.y;
                        cat[3]  += w * v1_.z; cat[4]  += w * v1_.w;
                        cat[5]  += w * v2_.x; cat[6]  += w * v2_.y;
                        cat[7]  += w * v2_.z; cat[8]  += w * v2_.w;
                        cat[9]  += w * v3_.x; cat[10] += w * v3_.y;
                        cat[11] += w * v3_.z; cat[12] += w * v3_.w;
                        cat[13] += w * v4_.x; cat[14] += w * v4_.y;
                        cat[15] += w * v4_.z;
                    } else {
                        a0 += w * bp[0];
                    }
                }
            }
        }
    }
}

// ---------------- K4: fused translate (T) + map_pred_stair (S) [+ map_pred (P)] ----
// WRITEP=true only when scratch is in d_ws (P region is then a pure output).
// maxpool3(translated ch0) is recomputed per neighbor via eval_pix<false>; a
// conservative rotated-window test short-circuits ~95% of pixels to streaming.
template<bool WRITEP>
__global__ void __launch_bounds__(256) k_translate(float* __restrict__ outp,
                                                   const float* __restrict__ smap,
                                                   const float* __restrict__ par,
                                                   const float* __restrict__ maps_last,
                                                   const float* __restrict__ eve) {
    int tid = blockIdx.x * blockDim.x + threadIdx.x;
    int b = tid / NPIX;
    int ij = tid % NPIX;
    int i = ij / NM, j = ij % NM;
    float c = par[b * 4 + 0], s = par[b * 4 + 1];
    float stx = par[b * 4 + 2], sty = par[b * 4 + 3];
    const float* smb = smap + (long long)b * 200000;
    const float* ml = maps_last + (long long)b * NC * NPIX;
    long long obase = (long long)b * NC * NPIX + ij;
    bool eve0 = (eve[b] == 0.0f);

    // conservative support test: own rotated center within window +/- margin 6
    // (tap q-deviation <= 2.2 px; neighbor center shift <= 1.5 px; margin 6 covers
    //  self AND all 8 neighbors -> outside: all 9 t0 == 0 exactly)
    float gxp = (((float)j + 0.5f) * 2.0f) / 480.0f - 1.0f + stx;
    float gyp = (((float)i + 0.5f) * 2.0f) / 480.0f - 1.0f + sty;
    float rxp = c * gxp - s * gyp, ryp = s * gxp + c * gyp;
    float qxc = (rxp + 1.0f) * 239.5f, qyc = (ryp + 1.0f) * 239.5f;
    bool near_ = (qxc > 184.0f) && (qxc < 296.0f) && (qyc > 234.0f) && (qyc < 346.0f);

    float a0 = 0.0f, a1 = 0.0f, as_ = 0.0f;
    float cat[16];
#pragma unroll
    for (int k = 0; k < 16; ++k) cat[k] = 0.0f;
    float mp = 0.0f;
    if (near_) {
        eval_pix<true>(i, j, smb, c, s, stx, sty, a0, a1, as_, cat);
        if constexpr (WRITEP) {
            mp = -INFINITY;
#pragma unroll
            for (int di = -1; di <= 1; ++di) {
                int ii = i + di;
                if (ii < 0 || ii >= NM) continue;
#pragma unroll
                for (int dj = -1; dj <= 1; ++dj) {
                    int jj = j + dj;
                    if (jj < 0 || jj >= NM) continue;
                    float b0, b1, b2;
                    if (di == 0 && dj == 0) b0 = a0;
                    else eval_pix<false>(ii, jj, smb, c, s, stx, sty, b0, b1, b2, nullptr);
                    mp = fmaxf(mp, b0);
                }
            }
        }
    }

    // cache maps_last channel values (used by S and P)
    float mlv[NC];
#pragma unroll
    for (int ch = 0; ch < NC; ++ch) mlv[ch] = ml[(long long)ch * NPIX + ij];

    // ---- translated (T) ----
    float* To = outp + T_OFF;
    To[obase] = a0;
    To[obase + (long long)NPIX] = a1;
    To[obase + 2LL * NPIX] = 0.0f;
    To[obase + 3LL * NPIX] = 0.0f;
#pragma unroll
    for (int k = 0; k < 16; ++k) To[obase + (long long)(4 + k) * NPIX] = cat[k];

    // ---- map_pred_stair (S) ----
    float ts0 = as_, t1s = a1;
    if (b == 0) {
        float dy = (float)i - par[32] + 0.5f;
        float dx = (float)j - par[33] + 0.5f;
        float mask = (dy * dy + dx * dx <= 900.0f) ? 1.0f : 0.0f;
        ts0 *= mask;
        t1s *= mask;
    }
    bool flagS = (t1s - ts0) > 0.8f;
    float* So = outp + S_OFF;
#pragma unroll
    for (int ch = 0; ch < NC; ++ch) {
        float tch = (ch == 0) ? ts0 : (ch == 1) ? t1s
                  : (ch < 4) ? 0.0f : cat[ch - 4];
        float m3 = fmaxf(mlv[ch], tch);
        So[obase + (long long)ch * NPIX] = (ch == 0 && eve0 && flagS) ? 0.0f : m3;
    }

    // ---- map_pred (P) ----
    if constexpr (WRITEP) {
        bool flagP = (a1 - mp) > 0.8f;
        float* Po = outp + P_OFF;
#pragma unroll
        for (int ch = 0; ch < NC; ++ch) {
            float tch = (ch == 0) ? a0 : (ch == 1) ? a1
                      : (ch < 4) ? 0.0f : cat[ch - 4];
            float m2 = fmaxf(mlv[ch], tch);
            Po[obase + (long long)ch * NPIX] = (ch == 0 && eve0 && flagP) ? 0.0f : m2;
        }
    }
}

// ---------------- K6 (fallback only): map_pred from stored T ----------------
__global__ void k_pred(const float* __restrict__ T, const float* __restrict__ maps_last,
                       const float* __restrict__ eve, float* __restrict__ outP) {
    int tid = blockIdx.x * blockDim.x + threadIdx.x;
    if (tid >= NBS * NPIX) return;
    int b = tid / NPIX;
    int ij = tid % NPIX;
    int i = ij / NM, j = ij % NM;
    const float* Tb = T + (long long)b * NC * NPIX;
    float mp = -INFINITY;
#pragma unroll
    for (int di = -1; di <= 1; ++di) {
        int ii = i + di;
        if (ii < 0 || ii >= NM) continue;
#pragma unroll
        for (int dj = -1; dj <= 1; ++dj) {
            int jj = j + dj;
            if (jj < 0 || jj >= NM) continue;
            mp = fmaxf(mp, Tb[(long long)ii * NM + jj]);
        }
    }
    float t1 = Tb[(long long)NPIX + ij];
    bool flag = (t1 - mp) > 0.8f;
    bool eve0 = (eve[b] == 0.0f);
    const float* ml = maps_last + (long long)b * NC * NPIX;
    long long obase = (long long)b * NC * NPIX + ij;
#pragma unroll
    for (int ch = 0; ch < NC; ++ch) {
        float m2 = fmaxf(ml[(long long)ch * NPIX + ij], Tb[(long long)ch * NPIX + ij]);
        outP[obase + (long long)ch * NPIX] = (ch == 0 && eve0 && flag) ? 0.0f : m2;
    }
}

extern "C" void kernel_launch(void* const* d_in, const int* in_sizes, int n_in,
                              void* d_out, int out_size, void* d_ws, size_t ws_size,
                              hipStream_t stream) {
    const float* obs = (const float*)d_in[0];
    const float* pose_obs = (const float*)d_in[1];
    const float* maps_last = (const float*)d_in[2];
    const float* poses_last = (const float*)d_in[3];
    const float* eve = (const float*)d_in[4];
    float* outp = (float*)d_out;

    // host-side exact camera focal constant (matches np.float64 -> f32)
    float camf = (float)(320.0 / tan(39.5 * M_PI / 180.0));

    // primary: all scratch in d_ws -> P region pure output -> fused map_pred
    bool useWS = (d_ws != nullptr) && (ws_size >= (size_t)SCR_END * 4);
    float* scr = useWS ? (float*)d_ws : (outp + P_OFF);

    float* smapp = scr + SMAP_O;
    float* par   = scr + PAR_O;
    float4* rec   = (float4*)(scr + REC_O);
    float4* epos  = (float4*)(scr + EPOS_O);
    float4* esem4 = (float4*)(scr + ESEM_O);
    unsigned int* counts = (unsigned int*)(scr + CNT_O);
    unsigned int* offs2  = (unsigned int*)(scr + OFF_O);
    unsigned int* curs   = (unsigned int*)(scr + CUR_O);

    // zero only the 320 KB bucket counters
    hipMemsetAsync(counts, 0, 80000 * sizeof(unsigned int), stream);

    k_pose<<<1, 64, 0, stream>>>(pose_obs, poses_last, outp + POSE_OFF, par);

    k_count<<<NPIXELS / 256, 256, 0, stream>>>(obs, eve, camf, counts, rec);

    k_scan<<<NBS, 1024, 0, stream>>>(counts, offs2, curs);

    k_fill<<<NPIXELS / 256, 256, 0, stream>>>(obs, rec, curs, epos, esem4);

    k_accum<<<NBS * 500, 256, 0, stream>>>(epos, esem4, counts, offs2, smapp);

    if (useWS) {
        k_translate<true><<<(NBS * NPIX) / 256, 256, 0, stream>>>(outp, smapp, par,
                                                                  maps_last, eve);
    } else {
        k_translate<false><<<(NBS * NPIX) / 256, 256, 0, stream>>>(outp, smapp, par,
                                                                   maps_last, eve);
        k_pred<<<(NBS * NPIX) / 256, 256, 0, stream>>>(outp + T_OFF, maps_last, eve,
                                                       outp + P_OFF);
    }
}

// Round 5
// 1087.924 us; speedup vs baseline: 1.3583x; 1.0377x over previous
//
#include <hip/hip_runtime.h>
#include <cmath>

// ---- problem constants ----
#define NBS 8
#define NC 20
#define NFH 480
#define NFW 640
#define NHS 240
#define NWS 320
#define NM 480
#define NPIX (NM * NM)   // 230400
#define NPIXELS (NBS * NHS * NWS)  // 614400
#define PPB (NHS * NWS)            // 76800 pixels per batch
#define CPB 4                      // columns (waves) per block in k_accum
#define CWORDS 752                 // 48 occ + 22*32 sem (rotated, folded at epilogue)

// ---- d_out layout (float element offsets) ----
// out = [translated (8,20,480,480) | map_pred | map_pred_stair | poses (8,3)]
constexpr long long T_OFF    = 0LL;
constexpr long long P_OFF    = 36864000LL;   // 8*20*230400
constexpr long long S_OFF    = 73728000LL;
constexpr long long POSE_OFF = 110592000LL;

// ---- scratch layout (float offsets relative to scratch base) ----
// Primary: scratch in d_ws (allows fusing map_pred -> no kernel touches scratch
// after it's dead). Fallback (ws too small): scratch in P region, separate k_pred.
constexpr long long SMAP_O = 0LL;                  // 8*10000*20 floats, [ij][20]
constexpr long long PAR_O  = SMAP_O + 1600000LL;   // 64 floats
constexpr long long REC_O  = PAR_O + 64LL;         // 614400 float4 (by tid)
constexpr long long EPOS_O = REC_O + 2457600LL;    // 614400 float4 (by slot)
constexpr long long ESEM_O = EPOS_O + 2457600LL;   // 614400*16 sem (by slot, rotated)
constexpr long long CNT_O  = ESEM_O + 9830400LL;   // 80000 u32 counts
constexpr long long OFF_O  = CNT_O + 80000LL;      // 80000 u32 offsets
constexpr long long CUR_O  = OFF_O + 80000LL;      // 80000 u32 cursors
constexpr long long SCR_END = CUR_O + 80000LL;     // 16,585,664 floats = 66.3 MB
// fallback fits: SCR_END < 36,864,000 (P region)  OK

__device__ __forceinline__ float clamp01(float x) {
    return fminf(fmaxf(x, 0.0f), 1.0f);
}

// shared projection math: single source of truth for pos/alive
__device__ __forceinline__ void project_px(const float* __restrict__ ob, float ev,
                                           float camf, int iy, int ix,
                                           float& posx, float& posy, float& posz,
                                           bool& alive, bool& semz) {
    float depth = ob[(3LL * NFH + 2 * iy) * NFW + 2 * ix];
    float th = ev * 0.017453292519943295f;
    float ct = cosf(th), st = sinf(th);
    float X = ((float)(2 * ix) - 319.5f) * depth / camf;
    float Z = ((float)(479 - 2 * iy) - 239.5f) * depth / camf;
    float Yr = ct * depth - st * Z;
    float Zr = st * depth + ct * Z + 88.0f;
    float Xs = X + 250.0f;
    float cx = ((Xs / 5.0f) - 50.0f) / 100.0f * 2.0f;
    float cy = ((Yr / 5.0f) - 50.0f) / 100.0f * 2.0f;
    float cz = ((Zr / 5.0f) - 16.0f) / 48.0f * 2.0f;
    posx = (cx * 100.0f) / 2.0f + 50.0f;
    posy = (cy * 100.0f) / 2.0f + 50.0f;
    posz = (cz * 48.0f) / 2.0f + 24.0f;
    alive = (posx > 0.0f) && (posx < 100.0f) &&
            (posy > 0.0f) && (posy < 100.0f) &&
            (posz > 0.0f) && (posz < 48.0f);
    semz = (posz > 12.0f) && (posz < 35.0f);
}

// ---------------- K1: poses + affine params ----------------
__global__ void k_pose(const float* __restrict__ pose_obs,
                       const float* __restrict__ poses_last,
                       float* __restrict__ pose_out,
                       float* __restrict__ par) {
    int b = threadIdx.x;
    if (b >= NBS) return;
    const float DEGf = 57.29577951308232f;
    float tr = poses_last[b * 3 + 2] / DEGf;
    float s_tr = sinf(tr), c_tr = cosf(tr);
    float ny = poses_last[b * 3 + 1] + pose_obs[b * 3 + 0] * s_tr + pose_obs[b * 3 + 1] * c_tr;
    float nx = poses_last[b * 3 + 0] + pose_obs[b * 3 + 0] * c_tr - pose_obs[b * 3 + 1] * s_tr;
    float no = poses_last[b * 3 + 2] + pose_obs[b * 3 + 2] * DEGf;
    no = fmodf(no - 180.0f, 360.0f) + 180.0f;
    no = fmodf(no + 180.0f, 360.0f) - 180.0f;
    pose_out[b * 3 + 0] = nx;
    pose_out[b * 3 + 1] = ny;
    pose_out[b * 3 + 2] = no;
    float stx = -((nx * 100.0f) / 5.0f - 240.0f) / 240.0f;
    float sty = -((ny * 100.0f) / 5.0f - 240.0f) / 240.0f;
    float stt = ((90.0f - no) * 3.14159265358979323846f) / 180.0f;
    par[b * 4 + 0] = cosf(stt);
    par[b * 4 + 1] = sinf(stt);
    par[b * 4 + 2] = stx;
    par[b * 4 + 3] = sty;
    if (b == 0) {
        int sy = (int)((ny * 100.0f) / 5.0f);   // truncation matches astype(int32)
        int sx = (int)((nx * 100.0f) / 5.0f);
        sy = min(max(sy, 30), NM - 31);
        sx = min(max(sx, 30), NM - 31);
        par[32] = (float)sy;
        par[33] = (float)sx;
    }
}

// ---------------- K2a: project pixels, write rec, count per bucket ----------------
__global__ void k_count(const float* __restrict__ obs,
                        const float* __restrict__ eve, float camf,
                        unsigned int* __restrict__ counts,
                        float4* __restrict__ rec) {
    int tid = blockIdx.x * blockDim.x + threadIdx.x;
    if (tid >= NPIXELS) return;
    int b = tid / PPB;
    int p = tid % PPB;
    int iy = p / NWS, ix = p % NWS;
    const float* ob = obs + (long long)b * NC * NFH * NFW;
    float posx, posy, posz;
    bool alive, semz;
    project_px(ob, eve[b], camf, iy, ix, posx, posy, posz, alive, semz);
    float flag = alive ? (semz ? 2.0f : 1.0f) : 0.0f;
    rec[tid] = make_float4(posx, posy, posz, flag);
    if (!alive) return;
    int fx = (int)floorf(posx);   // in [0,99]
    int fy = (int)floorf(posy);
    atomicAdd(&counts[b * 10000 + fx * 100 + fy], 1u);
}

// ---------------- K2b: per-batch exclusive prefix sum (single-pass block scan) ----------------
__global__ void __launch_bounds__(1024) k_scan(const unsigned int* __restrict__ counts,
                                               unsigned int* __restrict__ offs,
                                               unsigned int* __restrict__ curs) {
    int b = blockIdx.x;          // 8 blocks
    int t = threadIdx.x;         // 1024
    int lane = t & 63, wid = t >> 6;
    const unsigned int* cb = counts + b * 10000;
    unsigned int base_i = (unsigned int)t * 10u;
    unsigned int v[10];
    unsigned int s = 0;
#pragma unroll
    for (int k = 0; k < 10; ++k) {
        unsigned int i = base_i + (unsigned int)k;
        unsigned int x = (i < 10000u) ? cb[i] : 0u;
        v[k] = s;                // exclusive within thread
        s += x;
    }
    unsigned int incl = s;
#pragma unroll
    for (int d = 1; d < 64; d <<= 1) {
        unsigned int u = __shfl_up(incl, d);
        if (lane >= d) incl += u;
    }
    __shared__ unsigned int wtot[16];
    __shared__ unsigned int wexc[16];
    if (lane == 63) wtot[wid] = incl;
    __syncthreads();
    if (t == 0) {
        unsigned int a = 0;
        for (int i = 0; i < 16; ++i) { wexc[i] = a; a += wtot[i]; }
    }
    __syncthreads();
    unsigned int tbase = wexc[wid] + (incl - s);
#pragma unroll
    for (int k = 0; k < 10; ++k) {
        unsigned int i = base_i + (unsigned int)k;
        if (i < 10000u) {
            unsigned int e = tbase + v[k];
            offs[b * 10000 + i] = e;
            curs[b * 10000 + i] = e;
        }
    }
}

// ---------------- K2c: fill SoA bucket entries (pos float4 + rotated 16-float sem) --
// Sem stored pre-rotated by r = slot & 15: stored[k] = sem[(k + r) & 15]. This lets
// k_accum do conflict-free LDS adds with static register indices (see k_accum).
__global__ void k_fill(const float* __restrict__ obs,
                       const float4* __restrict__ rec,
                       unsigned int* __restrict__ curs,
                       float4* __restrict__ epos,
                       float4* __restrict__ esem4) {
    int tid = blockIdx.x * blockDim.x + threadIdx.x;
    if (tid >= NPIXELS) return;
    float4 r = rec[tid];
    if (r.w == 0.0f) return;
    int b = tid / PPB;
    int p = tid % PPB;
    int iy = p / NWS, ix = p % NWS;
    int fx = (int)floorf(r.x);
    int fy = (int)floorf(r.y);
    unsigned int slot = atomicAdd(&curs[b * 10000 + fx * 100 + fy], 1u);
    long long gslot = (long long)b * PPB + slot;
    epos[gslot] = make_float4(r.x, r.y, r.z, 0.0f);
    if (r.w == 2.0f) {  // sem needed: 2x2 mean pool of channels 4..19, rotated store
        const float* ob = obs + (long long)b * NC * NFH * NFW;
        int rrot = (int)(slot & 15u);
        float srot[16];
#pragma unroll
        for (int k = 0; k < 16; ++k) {
            int kk = (k + rrot) & 15;   // rotation folded into load address (no spill)
            const float* q = ob + ((long long)(4 + kk) * NFH + 2 * iy) * NFW + 2 * ix;
            srot[k] = (q[0] + q[1] + q[NFW] + q[NFW + 1]) * 0.25f;
        }
#pragma unroll
        for (int g = 0; g < 4; ++g)
            esem4[gslot * 4 + g] =
                make_float4(srot[4 * g], srot[4 * g + 1], srot[4 * g + 2], srot[4 * g + 3]);
    }
}

// ---------------- K2d: per-column wave gather-accumulate + fused z-projection ----------------
// 4 independent waves per block, one voxel column each (wave-private LDS acc ->
// no cross-wave contention). Sem adds use per-entry rotation: entry's stored
// value sr[s] goes to address base + (idx&15) + s (32-wide slot, no wrap), so
// active lanes hit distinct banks/addresses unless idx1==idx2 (mod 16) AND same z.
// Epilogue folds the two 16-halves, rounds, projects, writes interleaved smap [ij][20].
__global__ void __launch_bounds__(256) k_accum(const float4* __restrict__ epos,
                                               const float4* __restrict__ esem4,
                                               const unsigned int* __restrict__ counts,
                                               const unsigned int* __restrict__ offs,
                                               float* __restrict__ smap) {
    int wid = threadIdx.x >> 6, lane = threadIdx.x & 63;
    int col = blockIdx.x * CPB + wid;     // 0..79999
    int b = col / 10000;
    int xy = col % 10000;
    int x = xy / 100, y = xy % 100;
    __shared__ float acc[CPB][CWORDS];    // 12 KB total
    float* A = acc[wid];
    for (int i = lane; i < CWORDS; i += 64) A[i] = 0.0f;
    __syncthreads();
    if (x >= 1 && y >= 1) {               // column x==0 / y==0 never receives weight
        int base = b * 10000;
        int b00 = base + (x - 1) * 100 + (y - 1);
        int b01 = base + (x - 1) * 100 + y;
        int b10 = base + x * 100 + (y - 1);
        int b11 = base + x * 100 + y;
        unsigned int s0 = offs[b00];
        unsigned int n0 = offs[b01] + counts[b01] - s0;
        unsigned int s1 = offs[b10];
        unsigned int n1 = offs[b11] + counts[b11] - s1;
        unsigned int E = n0 + n1;
        const float4* pb = epos + (long long)b * PPB;
        const float4* sb = esem4 + (long long)b * PPB * 4;
        float fx_ = (float)x, fy_ = (float)y;
        for (unsigned int t = lane; t < E; t += 64) {
            unsigned int idx = (t < n0) ? (s0 + t) : (s1 + (t - n0));
            float4 e = pb[idx];
            float wx = 1.0f - fabsf(e.x - fx_);
            float wy = 1.0f - fabsf(e.y - fy_);
            float wxy = wx * wy;
            if (wxy <= 0.0f) continue;
            float posz = e.z;
            float fz = floorf(posz);
            bool zsem = (posz > 12.0f) && (posz < 35.0f);
            float sr[16];
            if (zsem) {
                const float4* sp = sb + (long long)idx * 4;
                float4 q0 = sp[0], q1 = sp[1], q2 = sp[2], q3 = sp[3];
                sr[0] = q0.x;  sr[1] = q0.y;  sr[2] = q0.z;  sr[3] = q0.w;
                sr[4] = q1.x;  sr[5] = q1.y;  sr[6] = q1.z;  sr[7] = q1.w;
                sr[8] = q2.x;  sr[9] = q2.y;  sr[10] = q2.z; sr[11] = q2.w;
                sr[12] = q3.x; sr[13] = q3.y; sr[14] = q3.z; sr[15] = q3.w;
            }
            int rbase = (int)(idx & 15u);
#pragma unroll
            for (int d = 0; d < 2; ++d) {
                float zf = fz + (float)d;
                int z = (int)zf;
                if (z < 1 || z > 47) continue;
                float w = wxy * (1.0f - fabsf(posz - zf));
                if (w == 0.0f) continue;
                atomicAdd(&A[z], w);          // occupancy
                if (z >= 13 && z < 35) {
                    float* ap = A + 48 + (z - 13) * 32 + rbase;
#pragma unroll
                    for (int s2 = 0; s2 < 16; ++s2)
                        atomicAdd(ap + s2, sr[s2] * w);   // static idx, rotated addr
                }
            }
        }
    }
    __syncthreads();
    // fused fold + rounding + projections -> interleaved smap [ij][20]
    float* smb = smap + (long long)b * 200000;
    int ij = y * 100 + x;
    if (lane < 20) {
        float s = 0.0f;
        if (lane == 0) {                        // fp_map (MAP_T = 1)
            for (int z = 13; z < 35; ++z) s += rintf(A[z]);
            s = clamp01(s);
        } else if (lane == 1) {                 // fp_exp (EXP_T = 1)
            for (int z = 0; z < 48; ++z) s += rintf(A[z]);
            s = clamp01(s);
        } else if (lane == 2) {                 // fp_stair
            for (int z = 20; z < 25; ++z) s += rintf(A[z]);
            s = clamp01(s);
        } else if (lane < 19) {                 // cat k (CAT_T = 5)
            int k = lane - 3;
            for (int zi = 0; zi < 22; ++zi)
                s += rintf(A[48 + zi * 32 + k] + A[48 + zi * 32 + 16 + k]);
            s = clamp01(s / 5.0f);
        }                                       // lane 19 = pad (0)
        smb[(long long)ij * 20 + lane] = s;
    }
}

// ---------------- tap evaluation: rotate+translate double grid_sample ----------------
// FULL: accumulate all 19 channels; else ch0 only. Accumulation order identical in
// both instantiations (tap order), so ch0 values are bit-identical across them.
template<bool FULL>
__device__ __forceinline__ void eval_pix(int i, int j, const float* __restrict__ smb,
                                         float c, float s, float stx, float sty,
                                         float& a0, float& a1, float& as_, float* cat) {
    a0 = 0.0f; a1 = 0.0f; as_ = 0.0f;
    float gx = (((float)j + 0.5f) * 2.0f) / 480.0f - 1.0f;
    float gy = (((float)i + 0.5f) * 2.0f) / 480.0f - 1.0f;
    float px = ((gx + stx) + 1.0f) * 479.0f / 2.0f;
    float py = ((gy + sty) + 1.0f) * 479.0f / 2.0f;
    float x0 = floorf(px), y0 = floorf(py);
    float wx1 = px - x0, wx0 = 1.0f - wx1;
    float wy1 = py - y0, wy0 = 1.0f - wy1;
#pragma unroll
    for (int t = 0; t < 4; ++t) {  // outer taps in reference gather order
        int ox = t & 1, oy = t >> 1;
        float xo = x0 + (float)ox, yo = y0 + (float)oy;
        if (!(xo >= 0.0f && xo < 480.0f && yo >= 0.0f && yo < 480.0f)) continue;
        float wo = (ox ? wx1 : wx0) * (oy ? wy1 : wy0);
        int ixo = (int)xo, iyo = (int)yo;
        float gx2 = (((float)ixo + 0.5f) * 2.0f) / 480.0f - 1.0f;
        float gy2 = (((float)iyo + 0.5f) * 2.0f) / 480.0f - 1.0f;
        float rx = c * gx2 - s * gy2;
        float ry = s * gx2 + c * gy2;
        float qx = (rx + 1.0f) * 479.0f / 2.0f;
        float qy = (ry + 1.0f) * 479.0f / 2.0f;
        float xq0 = floorf(qx), yq0 = floorf(qy);
        float u1 = qx - xq0, u0 = 1.0f - u1;
        float v1 = qy - yq0, v0 = 1.0f - v1;
#pragma unroll
        for (int t2 = 0; t2 < 4; ++t2) {
            int ax = t2 & 1, ay = t2 >> 1;
            float xa = xq0 + (float)ax, ya = yq0 + (float)ay;
            // agent_view nonzero window: rows [240,340), cols [190,290)
            if (xa >= 190.0f && xa < 290.0f && ya >= 240.0f && ya < 340.0f) {
                float w = wo * ((ax ? u1 : u0) * (ay ? v1 : v0));
                if (w != 0.0f) {
                    int o = ((int)ya - 240) * 100 + ((int)xa - 190);
                    const float* bp = smb + (long long)o * 20;
                    if constexpr (FULL) {
                        const float4* b4 = (const float4*)bp;
                        float4 v0_ = b4[0], v1_ = b4[1], v2_ = b4[2], v3_ = b4[3], v4_ = b4[4];
                        a0 += w * v0_.x; a1 += w * v0_.y; as_ += w * v0_.z;
                        cat[0]  += w * v0_.w;
                        cat[1]  += w * v1_.x; cat[2]  += w * v1_.y;
                        cat[3]  += w * v1_.z; cat[4]  += w * v1_.w;
                        cat[5]  += w * v2_.x; cat[6]  += w * v2_.y;
                        cat[7]  += w * v2_.z; cat[8]  += w * v2_.w;
                        cat[9]  += w * v3_.x; cat[10] += w * v3_.y;
                        cat[11] += w * v3_.z; cat[12] += w * v3_.w;
                        cat[13] += w * v4_.x; cat[14] += w * v4_.y;
                        cat[15] += w * v4_.z;
                    } else {
                        a0 += w * bp[0];
                    }
                }
            }
        }
    }
}

// ---------------- K4: fused translate (T) + map_pred_stair (S) [+ map_pred (P)] ----
// WRITEP=true only when scratch is in d_ws (P region is then a pure output).
// maxpool3(translated ch0) is recomputed per neighbor via eval_pix<false>; a
// conservative rotated-window test short-circuits ~95% of pixels to streaming.
template<bool WRITEP>
__global__ void __launch_bounds__(256) k_translate(float* __restrict__ outp,
                                                   const float* __restrict__ smap,
                                                   const float* __restrict__ par,
                                                   const float* __restrict__ maps_last,
                                                   const float* __restrict__ eve) {
    int tid = blockIdx.x * blockDim.x + threadIdx.x;
    int b = tid / NPIX;
    int ij = tid % NPIX;
    int i = ij / NM, j = ij % NM;
    float c = par[b * 4 + 0], s = par[b * 4 + 1];
    float stx = par[b * 4 + 2], sty = par[b * 4 + 3];
    const float* smb = smap + (long long)b * 200000;
    const float* ml = maps_last + (long long)b * NC * NPIX;
    long long obase = (long long)b * NC * NPIX + ij;
    bool eve0 = (eve[b] == 0.0f);

    // conservative support test: own rotated center within window +/- margin 6
    // (tap q-deviation <= 2.2 px; neighbor center shift <= 1.5 px; margin 6 covers
    //  self AND all 8 neighbors -> outside: all 9 t0 == 0 exactly)
    float gxp = (((float)j + 0.5f) * 2.0f) / 480.0f - 1.0f + stx;
    float gyp = (((float)i + 0.5f) * 2.0f) / 480.0f - 1.0f + sty;
    float rxp = c * gxp - s * gyp, ryp = s * gxp + c * gyp;
    float qxc = (rxp + 1.0f) * 239.5f, qyc = (ryp + 1.0f) * 239.5f;
    bool near_ = (qxc > 184.0f) && (qxc < 296.0f) && (qyc > 234.0f) && (qyc < 346.0f);

    float a0 = 0.0f, a1 = 0.0f, as_ = 0.0f;
    float cat[16];
#pragma unroll
    for (int k = 0; k < 16; ++k) cat[k] = 0.0f;
    float mp = 0.0f;
    if (near_) {
        eval_pix<true>(i, j, smb, c, s, stx, sty, a0, a1, as_, cat);
        if constexpr (WRITEP) {
            mp = -INFINITY;
#pragma unroll
            for (int di = -1; di <= 1; ++di) {
                int ii = i + di;
                if (ii < 0 || ii >= NM) continue;
#pragma unroll
                for (int dj = -1; dj <= 1; ++dj) {
                    int jj = j + dj;
                    if (jj < 0 || jj >= NM) continue;
                    float b0, b1, b2;
                    if (di == 0 && dj == 0) b0 = a0;
                    else eval_pix<false>(ii, jj, smb, c, s, stx, sty, b0, b1, b2, nullptr);
                    mp = fmaxf(mp, b0);
                }
            }
        }
    }

    // cache maps_last channel values (used by S and P)
    float mlv[NC];
#pragma unroll
    for (int ch = 0; ch < NC; ++ch) mlv[ch] = ml[(long long)ch * NPIX + ij];

    // ---- translated (T) ----
    float* To = outp + T_OFF;
    To[obase] = a0;
    To[obase + (long long)NPIX] = a1;
    To[obase + 2LL * NPIX] = 0.0f;
    To[obase + 3LL * NPIX] = 0.0f;
#pragma unroll
    for (int k = 0; k < 16; ++k) To[obase + (long long)(4 + k) * NPIX] = cat[k];

    // ---- map_pred_stair (S) ----
    float ts0 = as_, t1s = a1;
    if (b == 0) {
        float dy = (float)i - par[32] + 0.5f;
        float dx = (float)j - par[33] + 0.5f;
        float mask = (dy * dy + dx * dx <= 900.0f) ? 1.0f : 0.0f;
        ts0 *= mask;
        t1s *= mask;
    }
    bool flagS = (t1s - ts0) > 0.8f;
    float* So = outp + S_OFF;
#pragma unroll
    for (int ch = 0; ch < NC; ++ch) {
        float tch = (ch == 0) ? ts0 : (ch == 1) ? t1s
                  : (ch < 4) ? 0.0f : cat[ch - 4];
        float m3 = fmaxf(mlv[ch], tch);
        So[obase + (long long)ch * NPIX] = (ch == 0 && eve0 && flagS) ? 0.0f : m3;
    }

    // ---- map_pred (P) ----
    if constexpr (WRITEP) {
        bool flagP = (a1 - mp) > 0.8f;
        float* Po = outp + P_OFF;
#pragma unroll
        for (int ch = 0; ch < NC; ++ch) {
            float tch = (ch == 0) ? a0 : (ch == 1) ? a1
                      : (ch < 4) ? 0.0f : cat[ch - 4];
            float m2 = fmaxf(mlv[ch], tch);
            Po[obase + (long long)ch * NPIX] = (ch == 0 && eve0 && flagP) ? 0.0f : m2;
        }
    }
}

// ---------------- K6 (fallback only): map_pred from stored T ----------------
__global__ void k_pred(const float* __restrict__ T, const float* __restrict__ maps_last,
                       const float* __restrict__ eve, float* __restrict__ outP) {
    int tid = blockIdx.x * blockDim.x + threadIdx.x;
    if (tid >= NBS * NPIX) return;
    int b = tid / NPIX;
    int ij = tid % NPIX;
    int i = ij / NM, j = ij % NM;
    const float* Tb = T + (long long)b * NC * NPIX;
    float mp = -INFINITY;
#pragma unroll
    for (int di = -1; di <= 1; ++di) {
        int ii = i + di;
        if (ii < 0 || ii >= NM) continue;
#pragma unroll
        for (int dj = -1; dj <= 1; ++dj) {
            int jj = j + dj;
            if (jj < 0 || jj >= NM) continue;
            mp = fmaxf(mp, Tb[(long long)ii * NM + jj]);
        }
    }
    float t1 = Tb[(long long)NPIX + ij];
    bool flag = (t1 - mp) > 0.8f;
    bool eve0 = (eve[b] == 0.0f);
    const float* ml = maps_last + (long long)b * NC * NPIX;
    long long obase = (long long)b * NC * NPIX + ij;
#pragma unroll
    for (int ch = 0; ch < NC; ++ch) {
        float m2 = fmaxf(ml[(long long)ch * NPIX + ij], Tb[(long long)ch * NPIX + ij]);
        outP[obase + (long long)ch * NPIX] = (ch == 0 && eve0 && flag) ? 0.0f : m2;
    }
}

extern "C" void kernel_launch(void* const* d_in, const int* in_sizes, int n_in,
                              void* d_out, int out_size, void* d_ws, size_t ws_size,
                              hipStream_t stream) {
    const float* obs = (const float*)d_in[0];
    const float* pose_obs = (const float*)d_in[1];
    const float* maps_last = (const float*)d_in[2];
    const float* poses_last = (const float*)d_in[3];
    const float* eve = (const float*)d_in[4];
    float* outp = (float*)d_out;

    // host-side exact camera focal constant (matches np.float64 -> f32)
    float camf = (float)(320.0 / tan(39.5 * M_PI / 180.0));

    // primary: all scratch in d_ws -> P region pure output -> fused map_pred
    bool useWS = (d_ws != nullptr) && (ws_size >= (size_t)SCR_END * 4);
    float* scr = useWS ? (float*)d_ws : (outp + P_OFF);

    float* smapp = scr + SMAP_O;
    float* par   = scr + PAR_O;
    float4* rec   = (float4*)(scr + REC_O);
    float4* epos  = (float4*)(scr + EPOS_O);
    float4* esem4 = (float4*)(scr + ESEM_O);
    unsigned int* counts = (unsigned int*)(scr + CNT_O);
    unsigned int* offs2  = (unsigned int*)(scr + OFF_O);
    unsigned int* curs   = (unsigned int*)(scr + CUR_O);

    // zero only the 320 KB bucket counters
    hipMemsetAsync(counts, 0, 80000 * sizeof(unsigned int), stream);

    k_pose<<<1, 64, 0, stream>>>(pose_obs, poses_last, outp + POSE_OFF, par);

    k_count<<<NPIXELS / 256, 256, 0, stream>>>(obs, eve, camf, counts, rec);

    k_scan<<<NBS, 1024, 0, stream>>>(counts, offs2, curs);

    k_fill<<<NPIXELS / 256, 256, 0, stream>>>(obs, rec, curs, epos, esem4);

    k_accum<<<(NBS * 10000) / CPB, 256, 0, stream>>>(epos, esem4, counts, offs2,
                                                     smapp);

    if (useWS) {
        k_translate<true><<<(NBS * NPIX) / 256, 256, 0, stream>>>(outp, smapp, par,
                                                                  maps_last, eve);
    } else {
        k_translate<false><<<(NBS * NPIX) / 256, 256, 0, stream>>>(outp, smapp, par,
                                                                   maps_last, eve);
        k_pred<<<(NBS * NPIX) / 256, 256, 0, stream>>>(outp + T_OFF, maps_last, eve,
                                                       outp + P_OFF);
    }
}